// Round 11
// baseline (12126.414 us; speedup 1.0000x reference)
//
#include <hip/hip_runtime.h>

typedef unsigned short u16;
typedef unsigned int u32;
typedef __attribute__((ext_vector_type(8))) short bf16x8;
typedef __attribute__((ext_vector_type(4))) float f32x4;

#define SW(r) (((r) & 7) << 4)
#define RAW_BAR() { __builtin_amdgcn_s_barrier(); __builtin_amdgcn_sched_barrier(0); }
#define WAITV(N) { asm volatile("s_waitcnt vmcnt(" #N ")" ::: "memory"); __builtin_amdgcn_sched_barrier(0); }

__device__ __forceinline__ u16 f2bf(float f) {
  u32 x = __float_as_uint(f);
  x += 0x7fffu + ((x >> 16) & 1u);
  return (u16)(x >> 16);
}
__device__ __forceinline__ float bf2f(u16 h) { return __uint_as_float(((u32)h) << 16); }

__device__ __forceinline__ void gload_lds16(const void* g, void* l) {
  __builtin_amdgcn_global_load_lds(
      (const __attribute__((address_space(1))) u32*)g,
      (__attribute__((address_space(3))) u32*)l, 16, 0, 0);
}

// write-through 16B store: visible at L3 once vmcnt drains; L2 never dirty
__device__ __forceinline__ void cstore16(u16* p, bf16x8 v) {
  asm volatile("global_store_dwordx4 %0, %1, off sc0 sc1" :: "v"(p), "v"(v) : "memory");
}

__device__ __forceinline__ float fsigmoid(float x) { return 1.0f / (1.0f + __expf(-x)); }
__device__ __forceinline__ float ftanh(float x) {
  float a = fabsf(x);
  float t = __expf(-2.0f * a);
  float r = (1.0f - t) / (1.0f + t);
  return x < 0.0f ? -r : r;
}

// ---------------- prep: bf16 weight packs (WcatI gate-interleaved) ----------------
__global__ void seqenc_prep_w(
    const float* __restrict__ w0, const float* __restrict__ w1,
    const float* __restrict__ w2, const float* __restrict__ w3,
    const float* __restrict__ wih, const float* __restrict__ whh,
    const float* __restrict__ bih, const float* __restrict__ bhh,
    const float* __restrict__ wq, const float* __restrict__ wk, const float* __restrict__ wv,
    const float* __restrict__ bq, const float* __restrict__ bk, const float* __restrict__ bv,
    const float* __restrict__ wout,
    u16* __restrict__ WcatI, u16* __restrict__ Wqkv,
    u16* __restrict__ W0p, u16* __restrict__ W1b, u16* __restrict__ W2b,
    u16* __restrict__ W3b, u16* __restrict__ WoutB,
    float* __restrict__ bgI, float* __restrict__ bqkv)
{
  const long NC = 524288L, NQ = 196608L, N0P = 98304L;
  const long N1 = 262144L, N2 = 262144L, N3 = 131072L, NO = 65536L;
  const long NBG = 1024L, NBQ = 768L;
  const long TOT = NC + NQ + N0P + N1 + N2 + N3 + NO + NBG + NBQ;
  for (long i = (long)blockIdx.x * blockDim.x + threadIdx.x; i < TOT;
       i += (long)gridDim.x * blockDim.x) {
    long j = i;
    if (j < NC) {  // WcatI[1024][512], n = (c>>4)*64 + g*16 + (c&15)
      long n = j >> 9, k = j & 511;
      int g = (int)((n & 63) >> 4);
      int c = (int)((n >> 6) * 16 + (n & 15));
      long orig = g * 256 + c;
      float v = (k < 256) ? wih[orig * 256 + k] : whh[orig * 256 + (k - 256)];
      WcatI[j] = f2bf(v); continue;
    }
    j -= NC;
    if (j < NQ) {  // Wqkv[768][256]
      long n = j >> 8, k = j & 255;
      float v = (n < 256) ? wq[n * 256 + k] : (n < 512) ? wk[(n - 256) * 256 + k]
                                                        : wv[(n - 512) * 256 + k];
      Wqkv[j] = f2bf(v); continue;
    }
    j -= NQ;
    if (j < N0P) {
      long n = j / 192, k = j - n * 192;
      W0p[j] = f2bf(k < 160 ? w0[n * 160 + k] : 0.0f); continue;
    }
    j -= N0P;
    if (j < N1) { W1b[j] = f2bf(w1[j]); continue; }
    j -= N1;
    if (j < N2) { W2b[j] = f2bf(w2[j]); continue; }
    j -= N2;
    if (j < N3) { W3b[j] = f2bf(w3[j]); continue; }
    j -= N3;
    if (j < NO) { WoutB[j] = f2bf(wout[j]); continue; }
    j -= NO;
    if (j < NBG) {
      int g = (int)((j & 63) >> 4);
      int c = (int)((j >> 6) * 16 + (j & 15));
      long orig = g * 256 + c;
      bgI[j] = bih[orig] + bhh[orig]; continue;
    }
    j -= NBG;
    bqkv[j] = (j < 256) ? bq[j] : (j < 512) ? bk[j - 256] : bv[j - 512];
  }
}

// ---------------- prep: per-chunk padded concat input ----------------
__global__ void seqenc_prep_x(
    const float* __restrict__ state, const float* __restrict__ actions,
    u16* __restrict__ XpadC, int t0)
{
  const int TOT = 32768 * 192;
  for (int i = blockIdx.x * blockDim.x + threadIdx.x; i < TOT;
       i += gridDim.x * blockDim.x) {
    int row = i / 192, col = i - row * 192;
    int tl = row >> 9, r = row & 511;
    int t = t0 + tl;
    int b = r >> 3, a = r & 7;
    float v = 0.0f;
    if (col < 128) v = state[((size_t)(b * 256 + t)) * 128 + col];
    else if (col < 160) v = actions[(((size_t)(b * 256 + t)) * 8 + a) * 32 + (col - 128)];
    XpadC[i] = f2bf(v);
  }
}

// ---------------- init: h0 -> bf16 into hbR ring slot 15 ----------------
__global__ void seqenc_init(const float* __restrict__ h0, u16* __restrict__ hb15)
{
  int i = blockIdx.x * blockDim.x + threadIdx.x;
  if (i < 512 * 256) hb15[i] = f2bf(h0[i]);
}

// ---------------- MLP/out GEMM (depth-2 pipelined), modes 0/1/2 ----------------
__global__ __launch_bounds__(256) void seqenc_gemm(
    const u16* __restrict__ A1, const u16* __restrict__ A2, int K1, int lda,
    const u16* __restrict__ B, const float* __restrict__ bias,
    void* __restrict__ C, int ldc,
    int K, int N, int mode)
{
  __shared__ char As[2][16384];
  __shared__ char Bs[2][16384];
  const int tid = threadIdx.x;
  const int m0 = blockIdx.x * 128, n0 = blockIdx.y * 128;
  const int wid = tid >> 6, lane = tid & 63;
  const int wm = (wid >> 1) * 64, wn = (wid & 1) * 64;
  const int lr = lane & 15, kq = lane >> 4;
  f32x4 acc[4][4] = {};

  auto stage = [&](int tk, int buf) {
    int kt = tk << 6;
    const u16* Abase = (kt < K1) ? (A1 + kt) : (A2 + (kt - K1));
#pragma unroll
    for (int i2 = 0; i2 < 4; ++i2) {
      int q = i2 * 256 + tid;
      int r = q >> 3, cb = (q & 7) << 4;
      int scb = cb ^ SW(r);
      gload_lds16(Abase + (size_t)(m0 + r) * lda + (scb >> 1), As[buf] + q * 16);
      gload_lds16(B + (size_t)(n0 + r) * K + kt + (scb >> 1), Bs[buf] + q * 16);
    }
  };

  const int NT = K >> 6;
  stage(0, 0);
  int cur = 0;
  for (int t = 0; t < NT; ++t) {
    if (t + 1 < NT) { stage(t + 1, cur ^ 1); WAITV(8); }
    else { WAITV(0); }
    RAW_BAR();
#pragma unroll
    for (int ks = 0; ks < 2; ++ks) {
      bf16x8 af[4], bfr[4];
      int kb = ks * 64 + (kq << 4);
#pragma unroll
      for (int tt = 0; tt < 4; ++tt) {
        int ra = wm + tt * 16 + lr;
        af[tt] = *(const bf16x8*)(As[cur] + ra * 128 + (kb ^ SW(ra)));
        int rb = wn + tt * 16 + lr;
        bfr[tt] = *(const bf16x8*)(Bs[cur] + rb * 128 + (kb ^ SW(rb)));
      }
#pragma unroll
      for (int mt = 0; mt < 4; ++mt)
#pragma unroll
        for (int nt = 0; nt < 4; ++nt)
          acc[mt][nt] = __builtin_amdgcn_mfma_f32_16x16x32_bf16(af[mt], bfr[nt], acc[mt][nt], 0, 0, 0);
    }
    RAW_BAR();
    cur ^= 1;
  }

#pragma unroll
  for (int mt = 0; mt < 4; ++mt) {
#pragma unroll
    for (int nt = 0; nt < 4; ++nt) {
      int gn = n0 + wn + nt * 16 + lr;
      float bv = bias[gn];
#pragma unroll
      for (int rr = 0; rr < 4; ++rr) {
        int gm = m0 + wm + mt * 16 + (kq << 2) + rr;
        float v = acc[mt][nt][rr] + bv;
        if (mode == 1) v = fmaxf(v, 0.0f);
        if (mode == 2) ((float*)C)[(size_t)gm * ldc + gn] = v;
        else ((u16*)C)[(size_t)gm * ldc + gn] = f2bf(v);
      }
    }
  }
}

// ---------------- persistent recurrent loop: 32 WGs x 256 thr, 3 flag-barriers/step ----------------
// LDS pool layout (union):
//   G/Q phases: As[i] = pool + i*16384 (i<3), Bs[i] = pool + 49408 + i*16384
//   A phase:    scratch f32[16*516] = pool+0 (33024 B), spb = pool+33024 (16384 B)
//   G publish:  hl u16[128*32] = pool+33024 (8 KB)
//   Q publish:  stg u16[128][128] = pool+0 (32 KB)
// sosum f32[4096] separate (persists all steps).
__global__ __launch_bounds__(256) void seqenc_loop(
    const u16* __restrict__ X4, const u16* __restrict__ WcatI, const float* __restrict__ bgI,
    const u16* __restrict__ Wqkv, const float* __restrict__ bqkvp,
    const float* __restrict__ c0g,
    u16* hqR, u16* qkvR, u16* vtR, u16* hbR,
    float* __restrict__ osumG, u32* flags)
{
  __shared__ __align__(16) char pool[98560];
  __shared__ float sosum[4096];

  const int tid = threadIdx.x, wg = blockIdx.x;
  const int lane = tid & 63, wid = tid >> 6;
  const int lr = lane & 15, kq = lane >> 4;
  const int wm = (wid >> 1) * 64, wn = (wid & 1) * 64;

  auto AsB = [&](int i) { return pool + i * 16384; };
  auto BsB = [&](int i) { return pool + 49408 + i * 16384; };
  float* scratch = (float*)pool;
  char* spb = pool + 33024;

  // gates tile (1 per WG)
  const int gm0 = (wg >> 3) * 128, gn0 = (wg & 7) * 128;
  const int nbg = gn0 + wn;
  const int colb = (wn >> 6) << 4;
  const int cgbase = (gn0 >> 6) << 4;
  const int cg = cgbase + colb + lr;
  const float bi_ = bgI[nbg + lr];
  const float bf_ = bgI[nbg + 16 + lr];
  const float bg_ = bgI[nbg + 32 + lr];
  const float bo_ = bgI[nbg + 48 + lr];

  float c_reg[4][4];
#pragma unroll
  for (int mt = 0; mt < 4; ++mt)
#pragma unroll
    for (int rr = 0; rr < 4; ++rr)
      c_reg[mt][rr] = c0g[(size_t)(gm0 + wm + mt * 16 + (kq << 2) + rr) * 256 + cg];

  // qkv tile (WGs 0..23)
  const int qmi = wg & 3, qni = wg >> 2;
  const int qm0 = qmi * 128, qn0 = qni * 128;

  // attention rows
  const int ar0 = wg * 16;
  for (int i = tid; i < 4096; i += 256) sosum[i] = 0.0f;

  unsigned bcount = 0;
  // contention-free flag barrier: each WG stores its own flag; wave 0 polls all 32
  auto gbar = [&]() {
    ++bcount;
    __syncthreads();   // drains vmcnt -> all sc0sc1 stores (incl. prefetch) done
    if (tid < 64) {
      if (tid == 0) {
        u32 tv = bcount;
        asm volatile("global_store_dword %0, %1, off sc0 sc1"
                     :: "v"(flags + wg), "v"(tv) : "memory");
      }
      const u32* fp = flags + (tid & 31);
      unsigned sp = 0;
      for (;;) {
        u32 v;
        asm volatile("global_load_dword %0, %1, off sc0 sc1" : "=v"(v) : "v"(fp) : "memory");
        asm volatile("s_waitcnt vmcnt(0)" ::: "memory");
        if (__ballot(v >= bcount) == ~0ull) break;
        if (++sp > 50000000u) break;
        __builtin_amdgcn_s_sleep(2);
      }
    }
    __syncthreads();
  };

  // stage one K-tile of the gates GEMM (tiles 0-3: xt, tiles 4-7: hb)
  auto stageG = [&](const u16* xt, const u16* hb, int tk, int buf) {
    int kt = tk << 6;
    const u16* Abase = (kt < 256) ? (xt + kt) : (hb + (kt - 256));
#pragma unroll
    for (int i2 = 0; i2 < 4; ++i2) {
      int q = i2 * 256 + tid;
      int r = q >> 3, cb = (q & 7) << 4;
      int scb = cb ^ SW(r);
      gload_lds16(Abase + (size_t)(gm0 + r) * 256 + (scb >> 1), AsB(buf) + q * 16);
      gload_lds16(WcatI + (size_t)(gn0 + r) * 512 + kt + (scb >> 1), BsB(buf) + q * 16);
    }
  };

  // prologue: prefetch G tiles 0,1 for t=0 (xt + WcatI only)
  stageG(X4, nullptr, 0, 0);
  stageG(X4, nullptr, 1, 1);

  for (int t = 0; t < 256; ++t) {
    const int slot = t & 15, pslot = (t + 15) & 15;
    if (slot == 0) __builtin_amdgcn_fence(__ATOMIC_ACQUIRE, "agent");

    // ======== Phase G: gates GEMM (K=512, depth-3 pipeline) + LSTM epilogue ========
    {
      const u16* xt = X4 + (size_t)t * 131072;
      const u16* hb = hbR + (size_t)pslot * 131072;
      u16* hq = hqR + (size_t)slot * 131072;
      f32x4 acc[4][4] = {};
      // tiles 0,1 already resident (prefetched pre-barrier; barrier drained vmcnt)
      for (int tk = 0; tk < 8; ++tk) {
        if (tk + 2 < 8) { stageG(xt, hb, tk + 2, (tk + 2) % 3); WAITV(16); }
        else if (tk + 1 < 8) { WAITV(8); }
        else { WAITV(0); }
        RAW_BAR();
        const char* Ac = AsB(tk % 3);
        const char* Bc = BsB(tk % 3);
#pragma unroll
        for (int ks = 0; ks < 2; ++ks) {
          bf16x8 af[4], bfr[4];
          int kb = ks * 64 + (kq << 4);
#pragma unroll
          for (int tt = 0; tt < 4; ++tt) {
            int ra = wm + tt * 16 + lr;
            af[tt] = *(const bf16x8*)(Ac + ra * 128 + (kb ^ SW(ra)));
            int rb = wn + tt * 16 + lr;
            bfr[tt] = *(const bf16x8*)(Bc + rb * 128 + (kb ^ SW(rb)));
          }
#pragma unroll
          for (int mt = 0; mt < 4; ++mt)
#pragma unroll
            for (int nt = 0; nt < 4; ++nt)
              acc[mt][nt] = __builtin_amdgcn_mfma_f32_16x16x32_bf16(af[mt], bfr[nt], acc[mt][nt], 0, 0, 0);
        }
        RAW_BAR();
      }
      // LSTM epilogue -> LDS hl[128][32] -> coalesced write-through
      u16* hl = (u16*)spb;
#pragma unroll
      for (int mt = 0; mt < 4; ++mt) {
#pragma unroll
        for (int rr = 0; rr < 4; ++rr) {
          int row = wm + mt * 16 + (kq << 2) + rr;
          float i_ = fsigmoid(acc[mt][0][rr] + bi_);
          float f_ = fsigmoid(acc[mt][1][rr] + bf_);
          float g_ = ftanh(acc[mt][2][rr] + bg_);
          float o_ = fsigmoid(acc[mt][3][rr] + bo_);
          float cn = f_ * c_reg[mt][rr] + i_ * g_;
          float hn = o_ * ftanh(cn);
          c_reg[mt][rr] = cn;
          hl[row * 32 + colb + lr] = f2bf(hn);
        }
      }
      __syncthreads();
      {
        int base = tid * 16;
        int r = base >> 5, c = base & 31;
        u16* dst = hq + (size_t)(gm0 + r) * 256 + cgbase + c;
        cstore16(dst, *(bf16x8*)(hl + base));
        cstore16(dst + 8, *(bf16x8*)(hl + base + 8));
      }
    }
    gbar();

    // ======== Phase Q: qkv GEMM (K=256, depth-3), LDS-staged publish ========
    if (qni < 6) {
      const u16* hq = hqR + (size_t)slot * 131072;
      u16* qkv = qkvR + (size_t)slot * 262144;
      u16* vt = vtR + (size_t)slot * 131072;
      f32x4 acc[4][4] = {};
      auto stageQ = [&](int tk, int buf) {
        int kt = tk << 6;
#pragma unroll
        for (int i2 = 0; i2 < 4; ++i2) {
          int q = i2 * 256 + tid;
          int r = q >> 3, cb = (q & 7) << 4;
          int scb = cb ^ SW(r);
          gload_lds16(hq + (size_t)(qm0 + r) * 256 + kt + (scb >> 1), AsB(buf) + q * 16);
          gload_lds16(Wqkv + (size_t)(qn0 + r) * 256 + kt + (scb >> 1), BsB(buf) + q * 16);
        }
      };
      stageQ(0, 0);
      stageQ(1, 1);
      for (int tk = 0; tk < 4; ++tk) {
        if (tk + 2 < 4) { stageQ(tk + 2, (tk + 2) % 3); WAITV(16); }
        else if (tk + 1 < 4) { WAITV(8); }
        else { WAITV(0); }
        RAW_BAR();
        const char* Ac = AsB(tk % 3);
        const char* Bc = BsB(tk % 3);
#pragma unroll
        for (int ks = 0; ks < 2; ++ks) {
          bf16x8 af[4], bfr[4];
          int kb = ks * 64 + (kq << 4);
#pragma unroll
          for (int tt = 0; tt < 4; ++tt) {
            int ra = wm + tt * 16 + lr;
            af[tt] = *(const bf16x8*)(Ac + ra * 128 + (kb ^ SW(ra)));
            int rb = wn + tt * 16 + lr;
            bfr[tt] = *(const bf16x8*)(Bc + rb * 128 + (kb ^ SW(rb)));
          }
#pragma unroll
          for (int mt = 0; mt < 4; ++mt)
#pragma unroll
            for (int nt = 0; nt < 4; ++nt)
              acc[mt][nt] = __builtin_amdgcn_mfma_f32_16x16x32_bf16(af[mt], bfr[nt], acc[mt][nt], 0, 0, 0);
        }
        RAW_BAR();
      }
      u16* stg = (u16*)pool;  // 32 KB staging, XOR-swizzled rows
      if (qn0 < 512) {
#pragma unroll
        for (int mt = 0; mt < 4; ++mt)
#pragma unroll
          for (int nt = 0; nt < 4; ++nt) {
            int col = wn + nt * 16 + lr;
            float bv = bqkvp[qn0 + col];
#pragma unroll
            for (int rr = 0; rr < 4; ++rr) {
              int row = wm + mt * 16 + (kq << 2) + rr;
              *(u16*)((char*)stg + row * 256 + ((col * 2) ^ SW(row))) = f2bf(acc[mt][nt][rr] + bv);
            }
          }
        __syncthreads();
#pragma unroll
        for (int k = 0; k < 8; ++k) {
          int ch = tid + k * 256;
          int row = ch >> 4, cg2 = ch & 15;
          bf16x8 vv = *(bf16x8*)((char*)stg + row * 256 + ((cg2 * 16) ^ SW(row)));
          cstore16(qkv + (size_t)(qm0 + row) * 512 + qn0 + cg2 * 8, vv);
        }
      } else {
#pragma unroll
        for (int mt = 0; mt < 4; ++mt)
#pragma unroll
          for (int nt = 0; nt < 4; ++nt) {
            int dloc = wn + nt * 16 + lr;
            float bv = bqkvp[qn0 + dloc];
#pragma unroll
            for (int rr = 0; rr < 4; ++rr) {
              int kloc = wm + mt * 16 + (kq << 2) + rr;
              *(u16*)((char*)stg + dloc * 256 + ((kloc * 2) ^ SW(dloc))) = f2bf(acc[mt][nt][rr] + bv);
            }
          }
        __syncthreads();
#pragma unroll
        for (int k = 0; k < 8; ++k) {
          int ch = tid + k * 256;
          int dl = ch >> 4, cg2 = ch & 15;
          bf16x8 vv = *(bf16x8*)((char*)stg + dl * 256 + ((cg2 * 16) ^ SW(dl)));
          cstore16(vt + (size_t)(qn0 - 512 + dl) * 512 + qm0 + cg2 * 8, vv);
        }
      }
    }
    gbar();

    // ======== Phase A: attention, h'' = h' + PV, osum += ========
    {
      const u16* qkv = qkvR + (size_t)slot * 262144;
      const u16* vt = vtR + (size_t)slot * 131072;
      const u16* hq = hqR + (size_t)slot * 131072;
      u16* hb = hbR + (size_t)slot * 131072;
      // preload h' elements early (latency hides under S + softmax)
      u16 hql[4][4];
#pragma unroll
      for (int nt = 0; nt < 4; ++nt) {
        const int d0 = wid * 64 + nt * 16;
#pragma unroll
        for (int rr = 0; rr < 4; ++rr)
          hql[nt][rr] = hq[(size_t)(ar0 + kq * 4 + rr) * 256 + d0 + lr];
      }
      // S = q @ k^T
      {
        bf16x8 qf[8];
#pragma unroll
        for (int ks = 0; ks < 8; ++ks)
          qf[ks] = *(const bf16x8*)(qkv + (size_t)(ar0 + lr) * 512 + ks * 32 + (kq << 3));
#pragma unroll
        for (int nt = 0; nt < 8; ++nt) {
          const int key0 = wid * 128 + nt * 16;
          const u16* bp = qkv + (size_t)(key0 + lr) * 512 + 256 + (kq << 3);
          bf16x8 kf[8];
#pragma unroll
          for (int ks = 0; ks < 8; ++ks)
            kf[ks] = *(const bf16x8*)(bp + ks * 32);
          f32x4 a4 = {0.0f, 0.0f, 0.0f, 0.0f};
#pragma unroll
          for (int ks = 0; ks < 8; ++ks)
            a4 = __builtin_amdgcn_mfma_f32_16x16x32_bf16(qf[ks], kf[ks], a4, 0, 0, 0);
#pragma unroll
          for (int rr = 0; rr < 4; ++rr)
            scratch[(kq * 4 + rr) * 516 + key0 + lr] = a4[rr];
        }
      }
      __syncthreads();
      // softmax: 16 rows x 16 lanes, 32 vals/lane
      {
        int r = tid >> 4, l16 = tid & 15;
        float vals[32];
        float m = -3.4e38f;
#pragma unroll
        for (int j2 = 0; j2 < 32; ++j2) {
          vals[j2] = scratch[r * 516 + l16 + j2 * 16];
          m = fmaxf(m, vals[j2]);
        }
#pragma unroll
        for (int s2 = 8; s2 > 0; s2 >>= 1) m = fmaxf(m, __shfl_xor(m, s2, 16));
        float sum = 0.0f;
#pragma unroll
        for (int j2 = 0; j2 < 32; ++j2) {
          vals[j2] = __expf((vals[j2] - m) * 0.0625f);
          sum += vals[j2];
        }
#pragma unroll
        for (int s2 = 8; s2 > 0; s2 >>= 1) sum += __shfl_xor(sum, s2, 16);
        float inv = 1.0f / sum;
#pragma unroll
        for (int j2 = 0; j2 < 32; ++j2) {
          int c = l16 + j2 * 16;
          *(u16*)(spb + r * 1024 + ((c * 2) ^ SW(r))) = f2bf(vals[j2] * inv);
        }
      }
      __syncthreads();
      // PV + h'' -> LDS stage -> coalesced publish; osum +=
      {
        u16* stg2 = (u16*)scratch;  // [16][256] u16, XOR-swizzled (8 KB)
        bf16x8 pf[16];
#pragma unroll
        for (int ks = 0; ks < 16; ++ks)
          pf[ks] = *(const bf16x8*)(spb + lr * 1024 + ((ks * 64 + (kq << 4)) ^ SW(lr)));
#pragma unroll
        for (int nt = 0; nt < 4; ++nt) {
          const int d0 = wid * 64 + nt * 16;
          const u16* bp = vt + (size_t)(d0 + lr) * 512 + (kq << 3);
          f32x4 a4 = {0.0f, 0.0f, 0.0f, 0.0f};
          bf16x8 vf[8];
#pragma unroll
          for (int ks = 0; ks < 8; ++ks)
            vf[ks] = *(const bf16x8*)(bp + ks * 32);
#pragma unroll
          for (int ks = 0; ks < 8; ++ks)
            a4 = __builtin_amdgcn_mfma_f32_16x16x32_bf16(pf[ks], vf[ks], a4, 0, 0, 0);
#pragma unroll
          for (int ks = 0; ks < 8; ++ks)
            vf[ks] = *(const bf16x8*)(bp + 256 + ks * 32);
#pragma unroll
          for (int ks = 0; ks < 8; ++ks)
            a4 = __builtin_amdgcn_mfma_f32_16x16x32_bf16(pf[8 + ks], vf[ks], a4, 0, 0, 0);
#pragma unroll
          for (int rr = 0; rr < 4; ++rr) {
            int row = kq * 4 + rr, col = d0 + lr;
            float hn = bf2f(hql[nt][rr]) + a4[rr];
            *(u16*)((char*)stg2 + row * 512 + ((col * 2) ^ SW(row))) = f2bf(hn);
            sosum[row * 256 + col] += hn;
          }
        }
        __syncthreads();
#pragma unroll
        for (int k = 0; k < 2; ++k) {
          int ch = tid + k * 256;
          int row = ch >> 5, cg2 = ch & 31;
          bf16x8 vv = *(bf16x8*)((char*)stg2 + row * 512 + ((cg2 * 16) ^ SW(row)));
          cstore16(hb + (size_t)(ar0 + row) * 256 + cg2 * 8, vv);
        }
      }
    }
    // cross-barrier prefetch: next step's G tiles 0,1 (xt + WcatI only, no dataflow dep)
    __syncthreads();
    if (t + 1 < 256) {
      const u16* xtn = X4 + (size_t)(t + 1) * 131072;
      stageG(xtn, nullptr, 0, 0);
      stageG(xtn, nullptr, 1, 1);
    }
    gbar();
  }

  // dump osum
  __syncthreads();
  for (int i = tid; i < 4096; i += 256)
    osumG[(size_t)(ar0 + (i >> 8)) * 256 + (i & 255)] = sosum[i];
}

// ---------------- osum/256 -> bf16 ----------------
__global__ void seqenc_conv(const float* __restrict__ osum, u16* __restrict__ ob)
{
  int i = blockIdx.x * blockDim.x + threadIdx.x;
  if (i < 512 * 256) ob[i] = f2bf(osum[i] * (1.0f / 256.0f));
}

extern "C" void kernel_launch(void* const* d_in, const int* in_sizes, int n_in,
                              void* d_out, int out_size, void* d_ws, size_t ws_size,
                              hipStream_t stream) {
  (void)in_sizes; (void)n_in; (void)out_size; (void)ws_size;
  const float* state = (const float*)d_in[0];
  const float* actions = (const float*)d_in[1];
  const float* h0 = (const float*)d_in[2];
  const float* c0 = (const float*)d_in[3];
  const float* w0 = (const float*)d_in[4];
  const float* b0 = (const float*)d_in[5];
  const float* w1 = (const float*)d_in[6];
  const float* b1 = (const float*)d_in[7];
  const float* w2 = (const float*)d_in[8];
  const float* b2 = (const float*)d_in[9];
  const float* w3 = (const float*)d_in[10];
  const float* b3 = (const float*)d_in[11];
  const float* wih = (const float*)d_in[12];
  const float* whh = (const float*)d_in[13];
  const float* bih = (const float*)d_in[14];
  const float* bhh = (const float*)d_in[15];
  const float* wq = (const float*)d_in[16];
  const float* bq = (const float*)d_in[17];
  const float* wk = (const float*)d_in[18];
  const float* bk = (const float*)d_in[19];
  const float* wv = (const float*)d_in[20];
  const float* bv = (const float*)d_in[21];
  const float* wout = (const float*)d_in[22];
  const float* bout = (const float*)d_in[23];

  char* ws = (char*)d_ws;
  size_t off = 0;
  auto take = [&](size_t bytes) {
    off = (off + 255) & ~(size_t)255;
    char* p = ws + off;
    off += bytes;
    return p;
  };
  u16* XpadC = (u16*)take(32768UL * 192 * 2);
  u16* ping  = (u16*)take(32768UL * 512 * 2);
  u16* pong  = (u16*)take(32768UL * 512 * 2);
  u16* X4    = (u16*)take(131072UL * 256 * 2);
  u16* W0p   = (u16*)take(512UL * 192 * 2);
  u16* W1b   = (u16*)take(512UL * 512 * 2);
  u16* W2b   = (u16*)take(512UL * 512 * 2);
  u16* W3b   = (u16*)take(256UL * 512 * 2);
  u16* WcatI = (u16*)take(1024UL * 512 * 2);
  u16* Wqkv  = (u16*)take(768UL * 256 * 2);
  u16* WoutB = (u16*)take(256UL * 256 * 2);
  float* bgI   = (float*)take(1024UL * 4);
  float* bqkvp = (float*)take(768UL * 4);
  u16* hqR   = (u16*)take(16UL * 131072 * 2);   // h' ring
  u16* qkvR  = (u16*)take(16UL * 262144 * 2);   // q|k ring
  u16* vtR   = (u16*)take(16UL * 131072 * 2);   // v^T ring
  u16* hbR   = (u16*)take(16UL * 131072 * 2);   // h'' ring
  float* osumG = (float*)take(512UL * 256 * 4);
  u16* ob    = (u16*)take(512UL * 256 * 2);
  u32* flags = (u32*)take(256);

  hipMemsetAsync(flags, 0, 256, stream);
  seqenc_prep_w<<<1024, 256, 0, stream>>>(w0, w1, w2, w3, wih, whh, bih, bhh,
                                          wq, wk, wv, bq, bk, bv, wout,
                                          WcatI, Wqkv, W0p, W1b, W2b, W3b, WoutB, bgI, bqkvp);
  seqenc_init<<<512, 256, 0, stream>>>(h0, hbR + 15UL * 131072);

  const int CM = 32768;
  for (int c = 0; c < 4; ++c) {
    u16* x4c = X4 + (size_t)c * CM * 256;
    seqenc_prep_x<<<2048, 256, 0, stream>>>(state, actions, XpadC, c * 64);
    seqenc_gemm<<<dim3(CM / 128, 4), 256, 0, stream>>>(XpadC, XpadC, 192, 192, W0p, b0, ping, 512, 192, 512, 1);
    seqenc_gemm<<<dim3(CM / 128, 4), 256, 0, stream>>>(ping, ping, 512, 512, W1b, b1, pong, 512, 512, 512, 1);
    seqenc_gemm<<<dim3(CM / 128, 4), 256, 0, stream>>>(pong, pong, 512, 512, W2b, b2, ping, 512, 512, 512, 1);
    seqenc_gemm<<<dim3(CM / 128, 2), 256, 0, stream>>>(ping, ping, 512, 512, W3b, b3, x4c, 256, 512, 256, 0);
  }

  seqenc_loop<<<32, 256, 0, stream>>>(X4, WcatI, bgI, Wqkv, bqkvp, c0,
                                      hqR, qkvR, vtR, hbR, osumG, flags);

  seqenc_conv<<<512, 256, 0, stream>>>(osumG, ob);
  seqenc_gemm<<<dim3(4, 2), 256, 0, stream>>>(ob, ob, 256, 256, WoutB, bout, d_out, 256, 256, 256, 2);
}

// Round 13
// 11463.363 us; speedup vs baseline: 1.0578x; 1.0578x over previous
//
#include <hip/hip_runtime.h>

typedef unsigned short u16;
typedef unsigned int u32;
typedef __attribute__((ext_vector_type(8))) short bf16x8;
typedef __attribute__((ext_vector_type(4))) float f32x4;

#define SW(r) (((r) & 7) << 4)
#define RAW_BAR() { __builtin_amdgcn_s_barrier(); __builtin_amdgcn_sched_barrier(0); }
#define WAITV(N) { asm volatile("s_waitcnt vmcnt(" #N ")" ::: "memory"); __builtin_amdgcn_sched_barrier(0); }

__device__ __forceinline__ u16 f2bf(float f) {
  u32 x = __float_as_uint(f);
  x += 0x7fffu + ((x >> 16) & 1u);
  return (u16)(x >> 16);
}
__device__ __forceinline__ float bf2f(u16 h) { return __uint_as_float(((u32)h) << 16); }

__device__ __forceinline__ void gload_lds16(const void* g, void* l) {
  __builtin_amdgcn_global_load_lds(
      (const __attribute__((address_space(1))) u32*)g,
      (__attribute__((address_space(3))) u32*)l, 16, 0, 0);
}

__device__ __forceinline__ float fsigmoid(float x) { return 1.0f / (1.0f + __expf(-x)); }
__device__ __forceinline__ float ftanh(float x) {
  float a = fabsf(x);
  float t = __expf(-2.0f * a);
  float r = (1.0f - t) / (1.0f + t);
  return x < 0.0f ? -r : r;
}

// ---------------- prep: bf16 weight packs ----------------
// WcatI: gate-interleaved layout n = (c>>4)*64 + g*16 + (c&15); k: [w_ih | w_hh]
__global__ void seqenc_prep_w(
    const float* __restrict__ w0, const float* __restrict__ w1,
    const float* __restrict__ w2, const float* __restrict__ w3,
    const float* __restrict__ wih, const float* __restrict__ whh,
    const float* __restrict__ bih, const float* __restrict__ bhh,
    const float* __restrict__ wq, const float* __restrict__ wk, const float* __restrict__ wv,
    const float* __restrict__ bq, const float* __restrict__ bk, const float* __restrict__ bv,
    const float* __restrict__ wout,
    u16* __restrict__ WcatI, u16* __restrict__ Wqkv,
    u16* __restrict__ W0p, u16* __restrict__ W1b, u16* __restrict__ W2b,
    u16* __restrict__ W3b, u16* __restrict__ WoutB,
    float* __restrict__ bgI, float* __restrict__ bqkv)
{
  const long NC = 524288L, NQ = 196608L, N0P = 98304L;
  const long N1 = 262144L, N2 = 262144L, N3 = 131072L, NO = 65536L;
  const long NBG = 1024L, NBQ = 768L;
  const long TOT = NC + NQ + N0P + N1 + N2 + N3 + NO + NBG + NBQ;
  for (long i = (long)blockIdx.x * blockDim.x + threadIdx.x; i < TOT;
       i += (long)gridDim.x * blockDim.x) {
    long j = i;
    if (j < NC) {  // WcatI[1024][512]
      long n = j >> 9, k = j & 511;
      int g = (int)((n & 63) >> 4);
      int c = (int)((n >> 6) * 16 + (n & 15));
      long orig = g * 256 + c;
      float v = (k < 256) ? wih[orig * 256 + k] : whh[orig * 256 + (k - 256)];
      WcatI[j] = f2bf(v); continue;
    }
    j -= NC;
    if (j < NQ) {  // Wqkv[768][256]
      long n = j >> 8, k = j & 255;
      float v = (n < 256) ? wq[n * 256 + k] : (n < 512) ? wk[(n - 256) * 256 + k]
                                                        : wv[(n - 512) * 256 + k];
      Wqkv[j] = f2bf(v); continue;
    }
    j -= NQ;
    if (j < N0P) {  // W0p[512][192] zero-padded
      long n = j / 192, k = j - n * 192;
      W0p[j] = f2bf(k < 160 ? w0[n * 160 + k] : 0.0f); continue;
    }
    j -= N0P;
    if (j < N1) { W1b[j] = f2bf(w1[j]); continue; }
    j -= N1;
    if (j < N2) { W2b[j] = f2bf(w2[j]); continue; }
    j -= N2;
    if (j < N3) { W3b[j] = f2bf(w3[j]); continue; }
    j -= N3;
    if (j < NO) { WoutB[j] = f2bf(wout[j]); continue; }
    j -= NO;
    if (j < NBG) {  // bgI interleaved like WcatI rows
      int g = (int)((j & 63) >> 4);
      int c = (int)((j >> 6) * 16 + (j & 15));
      long orig = g * 256 + c;
      bgI[j] = bih[orig] + bhh[orig]; continue;
    }
    j -= NBG;
    bqkv[j] = (j < 256) ? bq[j] : (j < 512) ? bk[j - 256] : bv[j - 512];
  }
}

// ---------------- prep: per-chunk padded concat input (t in [t0, t0+64)) ----------------
__global__ void seqenc_prep_x(
    const float* __restrict__ state, const float* __restrict__ actions,
    u16* __restrict__ XpadC, int t0)
{
  const int TOT = 32768 * 192;
  for (int i = blockIdx.x * blockDim.x + threadIdx.x; i < TOT;
       i += gridDim.x * blockDim.x) {
    int row = i / 192, col = i - row * 192;
    int tl = row >> 9, r = row & 511;
    int t = t0 + tl;
    int b = r >> 3, a = r & 7;
    float v = 0.0f;
    if (col < 128) v = state[((size_t)(b * 256 + t)) * 128 + col];
    else if (col < 160) v = actions[(((size_t)(b * 256 + t)) * 8 + a) * 32 + (col - 128)];
    XpadC[i] = f2bf(v);
  }
}

// ---------------- state init ----------------
__global__ void seqenc_init(const float* __restrict__ h0, const float* __restrict__ c0,
                            u16* __restrict__ hbuf, float* __restrict__ cbuf,
                            float* __restrict__ osum)
{
  int i = blockIdx.x * blockDim.x + threadIdx.x;
  if (i < 512 * 256) {
    hbuf[i] = f2bf(h0[i]);
    cbuf[i] = c0[i];
    osum[i] = 0.0f;
  }
}

// ---------------- unified GEMM (depth-2 pipelined): C = A @ B^T + bias ----------------
// mode 0: bf16 out; 1: bf16 + relu; 2: f32 out; 3: bf16 out, cols>=512 transposed to vT.
__global__ __launch_bounds__(256) void seqenc_gemm(
    const u16* __restrict__ A1, const u16* __restrict__ A2, int K1, int lda,
    const u16* __restrict__ B, const float* __restrict__ bias,
    void* __restrict__ C, int ldc, u16* __restrict__ vT,
    int K, int N, int mode)
{
  __shared__ char As[2][16384];
  __shared__ char Bs[2][16384];
  const int tid = threadIdx.x;
  const int m0 = blockIdx.x * 128, n0 = blockIdx.y * 128;
  const int wid = tid >> 6, lane = tid & 63;
  const int wm = (wid >> 1) * 64, wn = (wid & 1) * 64;
  const int lr = lane & 15, kq = lane >> 4;
  f32x4 acc[4][4] = {};

  auto stage = [&](int tk, int buf) {
    int kt = tk << 6;
    const u16* Abase = (kt < K1) ? (A1 + kt) : (A2 + (kt - K1));
#pragma unroll
    for (int i2 = 0; i2 < 4; ++i2) {
      int q = i2 * 256 + tid;
      int r = q >> 3, cb = (q & 7) << 4;
      int scb = cb ^ SW(r);
      gload_lds16(Abase + (size_t)(m0 + r) * lda + (scb >> 1), As[buf] + q * 16);
      gload_lds16(B + (size_t)(n0 + r) * K + kt + (scb >> 1), Bs[buf] + q * 16);
    }
  };

  const int NT = K >> 6;
  stage(0, 0);
  int cur = 0;
  for (int t = 0; t < NT; ++t) {
    if (t + 1 < NT) { stage(t + 1, cur ^ 1); WAITV(8); }
    else { WAITV(0); }
    RAW_BAR();
#pragma unroll
    for (int ks = 0; ks < 2; ++ks) {
      bf16x8 af[4], bfr[4];
      int kb = ks * 64 + (kq << 4);
#pragma unroll
      for (int tt = 0; tt < 4; ++tt) {
        int ra = wm + tt * 16 + lr;
        af[tt] = *(const bf16x8*)(As[cur] + ra * 128 + (kb ^ SW(ra)));
        int rb = wn + tt * 16 + lr;
        bfr[tt] = *(const bf16x8*)(Bs[cur] + rb * 128 + (kb ^ SW(rb)));
      }
#pragma unroll
      for (int mt = 0; mt < 4; ++mt)
#pragma unroll
        for (int nt = 0; nt < 4; ++nt)
          acc[mt][nt] = __builtin_amdgcn_mfma_f32_16x16x32_bf16(af[mt], bfr[nt], acc[mt][nt], 0, 0, 0);
    }
    RAW_BAR();
    cur ^= 1;
  }

#pragma unroll
  for (int mt = 0; mt < 4; ++mt) {
#pragma unroll
    for (int nt = 0; nt < 4; ++nt) {
      int gn = n0 + wn + nt * 16 + lr;
      float bv = bias[gn];
#pragma unroll
      for (int rr = 0; rr < 4; ++rr) {
        int gm = m0 + wm + mt * 16 + (kq << 2) + rr;
        float v = acc[mt][nt][rr] + bv;
        if (mode == 1) v = fmaxf(v, 0.0f);
        if (mode == 2) {
          ((float*)C)[(size_t)gm * ldc + gn] = v;
        } else if (mode == 3 && gn >= 512) {
          vT[(size_t)(gn - 512) * 512 + gm] = f2bf(v);
        } else {
          ((u16*)C)[(size_t)gm * ldc + gn] = f2bf(v);
        }
      }
    }
  }
}

// ---------------- fused gates GEMM + LSTM pointwise ----------------
__global__ __launch_bounds__(256) void seqenc_gates_lstm(
    const u16* __restrict__ xt, const u16* __restrict__ hbuf,
    const u16* __restrict__ WcatI, const float* __restrict__ bgI,
    float* __restrict__ cbuf, u16* __restrict__ hq)
{
  __shared__ char As[2][16384];
  __shared__ char Bs[2][16384];
  const int tid = threadIdx.x;
  const int m0 = blockIdx.x * 128, n0 = blockIdx.y * 128;
  const int wid = tid >> 6, lane = tid & 63;
  const int wm = (wid >> 1) * 64, wn = (wid & 1) * 64;
  const int lr = lane & 15, kq = lane >> 4;
  const int K = 512, K1 = 256, lda = 256;
  f32x4 acc[4][4] = {};

  auto stage = [&](int tk, int buf) {
    int kt = tk << 6;
    const u16* Abase = (kt < K1) ? (xt + kt) : (hbuf + (kt - K1));
#pragma unroll
    for (int i2 = 0; i2 < 4; ++i2) {
      int q = i2 * 256 + tid;
      int r = q >> 3, cb = (q & 7) << 4;
      int scb = cb ^ SW(r);
      gload_lds16(Abase + (size_t)(m0 + r) * lda + (scb >> 1), As[buf] + q * 16);
      gload_lds16(WcatI + (size_t)(n0 + r) * K + kt + (scb >> 1), Bs[buf] + q * 16);
    }
  };

  const int NT = 8;
  stage(0, 0);
  int cur = 0;
  for (int t = 0; t < NT; ++t) {
    if (t + 1 < NT) { stage(t + 1, cur ^ 1); WAITV(8); }
    else { WAITV(0); }
    RAW_BAR();
#pragma unroll
    for (int ks = 0; ks < 2; ++ks) {
      bf16x8 af[4], bfr[4];
      int kb = ks * 64 + (kq << 4);
#pragma unroll
      for (int tt = 0; tt < 4; ++tt) {
        int ra = wm + tt * 16 + lr;
        af[tt] = *(const bf16x8*)(As[cur] + ra * 128 + (kb ^ SW(ra)));
        int rb = wn + tt * 16 + lr;
        bfr[tt] = *(const bf16x8*)(Bs[cur] + rb * 128 + (kb ^ SW(rb)));
      }
#pragma unroll
      for (int mt = 0; mt < 4; ++mt)
#pragma unroll
        for (int nt = 0; nt < 4; ++nt)
          acc[mt][nt] = __builtin_amdgcn_mfma_f32_16x16x32_bf16(af[mt], bfr[nt], acc[mt][nt], 0, 0, 0);
    }
    RAW_BAR();
    cur ^= 1;
  }

  // LSTM epilogue: acc[mt][g][rr] are the 4 gates of cell cg for row gm.
  const int nb = n0 + wn;
  const int cg = (nb >> 6) * 16 + lr;
  const float bi = bgI[nb + lr];
  const float bf = bgI[nb + 16 + lr];
  const float bgv = bgI[nb + 32 + lr];
  const float bo = bgI[nb + 48 + lr];
#pragma unroll
  for (int mt = 0; mt < 4; ++mt) {
#pragma unroll
    for (int rr = 0; rr < 4; ++rr) {
      int gm = m0 + wm + mt * 16 + (kq << 2) + rr;
      size_t gi = (size_t)gm * 256 + cg;
      float i_ = fsigmoid(acc[mt][0][rr] + bi);
      float f_ = fsigmoid(acc[mt][1][rr] + bf);
      float g_ = ftanh(acc[mt][2][rr] + bgv);
      float o_ = fsigmoid(acc[mt][3][rr] + bo);
      float cn = f_ * cbuf[gi] + i_ * g_;
      float hn = o_ * ftanh(cn);
      cbuf[gi] = cn;
      hq[gi] = f2bf(hn);
    }
  }
}

// ---------------- attention: 32 WGs x 16 rows; pipelined k/v loads ----------------
__global__ __launch_bounds__(512) void seqenc_attn(
    const u16* __restrict__ QKV, const u16* __restrict__ vT,
    const u16* __restrict__ hq, u16* __restrict__ hbuf, float* __restrict__ osum)
{
  __shared__ float scratch[16 * 516];
  __shared__ char spb[16 * 1024];
  const int tid = threadIdx.x;
  const int lane = tid & 63, wid = tid >> 6;
  const int lr = lane & 15, kq = lane >> 4;
  const int r0 = blockIdx.x * 16;

  // preload h' add-operands early (latency hides under S + softmax)
  u16 hql[2][4];
#pragma unroll
  for (int nt = 0; nt < 2; ++nt) {
    const int d0 = wid * 32 + nt * 16;
#pragma unroll
    for (int rr = 0; rr < 4; ++rr)
      hql[nt][rr] = hq[(size_t)(r0 + kq * 4 + rr) * 256 + d0 + lr];
  }

  bf16x8 vfp[8];  // pre-issued PV tile nt=0, ks 0..7 (hides under S + softmax)

  // S = q @ k^T with explicit 2-deep kf pipeline
  {
    bf16x8 qf[8];
#pragma unroll
    for (int ks = 0; ks < 8; ++ks)
      qf[ks] = *(const bf16x8*)(QKV + (size_t)(r0 + lr) * 768 + ks * 32 + (kq << 3));
    bf16x8 kf[2][8];
    {
      const u16* bp = QKV + (size_t)(wid * 64 + lr) * 768 + 256 + (kq << 3);
#pragma unroll
      for (int ks = 0; ks < 8; ++ks) kf[0][ks] = *(const bf16x8*)(bp + ks * 32);
    }
#pragma unroll
    for (int nt = 0; nt < 4; ++nt) {
      if (nt + 1 < 4) {
        const u16* bpn = QKV + (size_t)(wid * 64 + (nt + 1) * 16 + lr) * 768 + 256 + (kq << 3);
#pragma unroll
        for (int ks = 0; ks < 8; ++ks) kf[(nt + 1) & 1][ks] = *(const bf16x8*)(bpn + ks * 32);
      } else {
        // pre-issue PV tile 0's first half while last S tile computes
        const u16* vp0 = vT + (size_t)(wid * 32 + lr) * 512 + (kq << 3);
#pragma unroll
        for (int ks = 0; ks < 8; ++ks) vfp[ks] = *(const bf16x8*)(vp0 + ks * 32);
      }
      f32x4 a4 = {0.0f, 0.0f, 0.0f, 0.0f};
#pragma unroll
      for (int ks = 0; ks < 8; ++ks)
        a4 = __builtin_amdgcn_mfma_f32_16x16x32_bf16(qf[ks], kf[nt & 1][ks], a4, 0, 0, 0);
      const int key0 = wid * 64 + nt * 16;
#pragma unroll
      for (int rr = 0; rr < 4; ++rr)
        scratch[(kq * 4 + rr) * 516 + key0 + lr] = a4[rr];
    }
  }
  __syncthreads();

  // softmax (row-parallel over 32 lanes)
  {
    int r = tid >> 5, l32 = tid & 31;
    float vals[16];
    float m = -3.4e38f;
#pragma unroll
    for (int j2 = 0; j2 < 16; ++j2) {
      vals[j2] = scratch[r * 516 + l32 + j2 * 32];
      m = fmaxf(m, vals[j2]);
    }
#pragma unroll
    for (int s2 = 16; s2 > 0; s2 >>= 1) m = fmaxf(m, __shfl_xor(m, s2, 32));
    float sum = 0.0f;
#pragma unroll
    for (int j2 = 0; j2 < 16; ++j2) {
      vals[j2] = __expf((vals[j2] - m) * 0.0625f);
      sum += vals[j2];
    }
#pragma unroll
    for (int s2 = 16; s2 > 0; s2 >>= 1) sum += __shfl_xor(sum, s2, 32);
    float inv = 1.0f / sum;
#pragma unroll
    for (int j2 = 0; j2 < 16; ++j2) {
      int c = l32 + j2 * 32;
      *(u16*)(spb + r * 1024 + ((c * 2) ^ SW(r))) = f2bf(vals[j2] * inv);
    }
  }
  __syncthreads();

  // h'' = h' + P @ V (via vT), pipelined vf; osum += h''
  {
    bf16x8 pf[16];
#pragma unroll
    for (int ks = 0; ks < 16; ++ks)
      pf[ks] = *(const bf16x8*)(spb + lr * 1024 + ((ks * 64 + (kq << 4)) ^ SW(lr)));
    const u16* vp = vT + (size_t)(wid * 32 + lr) * 512 + (kq << 3);
    // tile 0: first 8 frags pre-issued (vfp); load second 8 now
    bf16x8 vfb[8];
#pragma unroll
    for (int ks = 0; ks < 8; ++ks) vfb[ks] = *(const bf16x8*)(vp + 256 + ks * 32);
    f32x4 a0 = {0.0f, 0.0f, 0.0f, 0.0f};
#pragma unroll
    for (int ks = 0; ks < 8; ++ks)
      a0 = __builtin_amdgcn_mfma_f32_16x16x32_bf16(pf[ks], vfp[ks], a0, 0, 0, 0);
    // issue tile 1 first half while tile 0 second half computes
#pragma unroll
    for (int ks = 0; ks < 8; ++ks) vfp[ks] = *(const bf16x8*)(vp + 8192 + ks * 32);
#pragma unroll
    for (int ks = 0; ks < 8; ++ks)
      a0 = __builtin_amdgcn_mfma_f32_16x16x32_bf16(pf[8 + ks], vfb[ks], a0, 0, 0, 0);
    // tile 1 second half
#pragma unroll
    for (int ks = 0; ks < 8; ++ks) vfb[ks] = *(const bf16x8*)(vp + 8448 + ks * 32);
    f32x4 a1 = {0.0f, 0.0f, 0.0f, 0.0f};
#pragma unroll
    for (int ks = 0; ks < 8; ++ks)
      a1 = __builtin_amdgcn_mfma_f32_16x16x32_bf16(pf[ks], vfp[ks], a1, 0, 0, 0);
#pragma unroll
    for (int ks = 0; ks < 8; ++ks)
      a1 = __builtin_amdgcn_mfma_f32_16x16x32_bf16(pf[8 + ks], vfb[ks], a1, 0, 0, 0);
    // write h'' + osum (tile 0 -> d0, tile 1 -> d0+16)
#pragma unroll
    for (int rr = 0; rr < 4; ++rr) {
      int row = kq * 4 + rr;
      int col0 = wid * 32 + lr;
      size_t gi0 = (size_t)(r0 + row) * 256 + col0;
      float hn0 = bf2f(hql[0][rr]) + a0[rr];
      hbuf[gi0] = f2bf(hn0);
      osum[gi0] += hn0;
      size_t gi1 = gi0 + 16;
      float hn1 = bf2f(hql[1][rr]) + a1[rr];
      hbuf[gi1] = f2bf(hn1);
      osum[gi1] += hn1;
    }
  }
}

// ---------------- osum/256 -> bf16 ----------------
__global__ void seqenc_conv(const float* __restrict__ osum, u16* __restrict__ ob)
{
  int i = blockIdx.x * blockDim.x + threadIdx.x;
  if (i < 512 * 256) ob[i] = f2bf(osum[i] * (1.0f / 256.0f));
}

extern "C" void kernel_launch(void* const* d_in, const int* in_sizes, int n_in,
                              void* d_out, int out_size, void* d_ws, size_t ws_size,
                              hipStream_t stream) {
  (void)in_sizes; (void)n_in; (void)out_size; (void)ws_size;
  const float* state = (const float*)d_in[0];
  const float* actions = (const float*)d_in[1];
  const float* h0 = (const float*)d_in[2];
  const float* c0 = (const float*)d_in[3];
  const float* w0 = (const float*)d_in[4];
  const float* b0 = (const float*)d_in[5];
  const float* w1 = (const float*)d_in[6];
  const float* b1 = (const float*)d_in[7];
  const float* w2 = (const float*)d_in[8];
  const float* b2 = (const float*)d_in[9];
  const float* w3 = (const float*)d_in[10];
  const float* b3 = (const float*)d_in[11];
  const float* wih = (const float*)d_in[12];
  const float* whh = (const float*)d_in[13];
  const float* bih = (const float*)d_in[14];
  const float* bhh = (const float*)d_in[15];
  const float* wq = (const float*)d_in[16];
  const float* bq = (const float*)d_in[17];
  const float* wk = (const float*)d_in[18];
  const float* bk = (const float*)d_in[19];
  const float* wv = (const float*)d_in[20];
  const float* bv = (const float*)d_in[21];
  const float* wout = (const float*)d_in[22];
  const float* bout = (const float*)d_in[23];

  char* ws = (char*)d_ws;
  size_t off = 0;
  auto take = [&](size_t bytes) {
    off = (off + 255) & ~(size_t)255;
    char* p = ws + off;
    off += bytes;
    return p;
  };
  u16* XpadC = (u16*)take(32768UL * 192 * 2);
  u16* ping  = (u16*)take(32768UL * 512 * 2);
  u16* pong  = (u16*)take(32768UL * 512 * 2);
  u16* X4    = (u16*)take(131072UL * 256 * 2);
  u16* W0p   = (u16*)take(512UL * 192 * 2);
  u16* W1b   = (u16*)take(512UL * 512 * 2);
  u16* W2b   = (u16*)take(512UL * 512 * 2);
  u16* W3b   = (u16*)take(256UL * 512 * 2);
  u16* WcatI = (u16*)take(1024UL * 512 * 2);
  u16* Wqkv  = (u16*)take(768UL * 256 * 2);
  u16* WoutB = (u16*)take(256UL * 256 * 2);
  float* bgI   = (float*)take(1024UL * 4);
  float* bqkvp = (float*)take(768UL * 4);
  u16* QKV   = (u16*)take(512UL * 768 * 2);
  u16* vT    = (u16*)take(256UL * 512 * 2);
  u16* hbuf  = (u16*)take(512UL * 256 * 2);   // h'' (post-attn), input to gates
  u16* hq    = (u16*)take(512UL * 256 * 2);   // h' (post-lstm), input to qkv/attn
  float* cbuf  = (float*)take(512UL * 256 * 4);
  float* osum  = (float*)take(512UL * 256 * 4);
  u16* ob    = (u16*)take(512UL * 256 * 2);

  seqenc_prep_w<<<1024, 256, 0, stream>>>(w0, w1, w2, w3, wih, whh, bih, bhh,
                                          wq, wk, wv, bq, bk, bv, wout,
                                          WcatI, Wqkv, W0p, W1b, W2b, W3b, WoutB, bgI, bqkvp);
  seqenc_init<<<512, 256, 0, stream>>>(h0, c0, hbuf, cbuf, osum);

  const int CM = 32768;
  for (int c = 0; c < 4; ++c) {
    u16* x4c = X4 + (size_t)c * CM * 256;
    seqenc_prep_x<<<2048, 256, 0, stream>>>(state, actions, XpadC, c * 64);
    seqenc_gemm<<<dim3(CM / 128, 4), 256, 0, stream>>>(XpadC, XpadC, 192, 192, W0p, b0, ping, 512, nullptr, 192, 512, 1);
    seqenc_gemm<<<dim3(CM / 128, 4), 256, 0, stream>>>(ping, ping, 512, 512, W1b, b1, pong, 512, nullptr, 512, 512, 1);
    seqenc_gemm<<<dim3(CM / 128, 4), 256, 0, stream>>>(pong, pong, 512, 512, W2b, b2, ping, 512, nullptr, 512, 512, 1);
    seqenc_gemm<<<dim3(CM / 128, 2), 256, 0, stream>>>(ping, ping, 512, 512, W3b, b3, x4c, 256, nullptr, 512, 256, 0);
  }

  for (int t = 0; t < 256; ++t) {
    const u16* xt = X4 + (size_t)t * 512 * 256;
    seqenc_gates_lstm<<<dim3(4, 8), 256, 0, stream>>>(xt, hbuf, WcatI, bgI, cbuf, hq);
    seqenc_gemm<<<dim3(4, 6), 256, 0, stream>>>(hq, hq, 256, 256, Wqkv, bqkvp, QKV, 768, vT, 256, 768, 3);
    seqenc_attn<<<32, 512, 0, stream>>>(QKV, vT, hq, hbuf, osum);
  }

  seqenc_conv<<<512, 256, 0, stream>>>(osum, ob);
  seqenc_gemm<<<dim3(4, 2), 256, 0, stream>>>(ob, ob, 256, 256, WoutB, bout, d_out, 256, nullptr, 256, 256, 2);
}

// Round 14
// 11065.717 us; speedup vs baseline: 1.0959x; 1.0359x over previous
//
#include <hip/hip_runtime.h>

typedef unsigned short u16;
typedef unsigned int u32;
typedef __attribute__((ext_vector_type(8))) short bf16x8;
typedef __attribute__((ext_vector_type(4))) float f32x4;

#define SW(r) (((r) & 7) << 4)
#define RAW_BAR() { __builtin_amdgcn_s_barrier(); __builtin_amdgcn_sched_barrier(0); }
#define WAITV(N) { asm volatile("s_waitcnt vmcnt(" #N ")" ::: "memory"); __builtin_amdgcn_sched_barrier(0); }

__device__ __forceinline__ u16 f2bf(float f) {
  u32 x = __float_as_uint(f);
  x += 0x7fffu + ((x >> 16) & 1u);
  return (u16)(x >> 16);
}
__device__ __forceinline__ float bf2f(u16 h) { return __uint_as_float(((u32)h) << 16); }

__device__ __forceinline__ void gload_lds16(const void* g, void* l) {
  __builtin_amdgcn_global_load_lds(
      (const __attribute__((address_space(1))) u32*)g,
      (__attribute__((address_space(3))) u32*)l, 16, 0, 0);
}

__device__ __forceinline__ float fsigmoid(float x) { return 1.0f / (1.0f + __expf(-x)); }
__device__ __forceinline__ float ftanh(float x) {
  float a = fabsf(x);
  float t = __expf(-2.0f * a);
  float r = (1.0f - t) / (1.0f + t);
  return x < 0.0f ? -r : r;
}

// ---------------- prep: bf16 weight packs ----------------
// WihI/WhhI: gate-interleaved rows n = (c>>4)*64 + g*16 + (c&15), K=256 each.
__global__ void seqenc_prep_w(
    const float* __restrict__ w0, const float* __restrict__ w1,
    const float* __restrict__ w2, const float* __restrict__ w3,
    const float* __restrict__ wih, const float* __restrict__ whh,
    const float* __restrict__ bih, const float* __restrict__ bhh,
    const float* __restrict__ wq, const float* __restrict__ wk, const float* __restrict__ wv,
    const float* __restrict__ bq, const float* __restrict__ bk, const float* __restrict__ bv,
    const float* __restrict__ wout,
    u16* __restrict__ WihI, u16* __restrict__ WhhI, u16* __restrict__ Wqkv,
    u16* __restrict__ W0p, u16* __restrict__ W1b, u16* __restrict__ W2b,
    u16* __restrict__ W3b, u16* __restrict__ WoutB,
    float* __restrict__ bgI, float* __restrict__ bqkv)
{
  const long NIH = 262144L, NHH = 262144L, NQ = 196608L, N0P = 98304L;
  const long N1 = 262144L, N2 = 262144L, N3 = 131072L, NO = 65536L;
  const long NBG = 1024L, NBQ = 768L;
  const long TOT = NIH + NHH + NQ + N0P + N1 + N2 + N3 + NO + NBG + NBQ;
  for (long i = (long)blockIdx.x * blockDim.x + threadIdx.x; i < TOT;
       i += (long)gridDim.x * blockDim.x) {
    long j = i;
    if (j < NIH) {  // WihI[1024][256]
      long n = j >> 8, k = j & 255;
      int g = (int)((n & 63) >> 4);
      int c = (int)((n >> 6) * 16 + (n & 15));
      WihI[j] = f2bf(wih[(long)(g * 256 + c) * 256 + k]); continue;
    }
    j -= NIH;
    if (j < NHH) {  // WhhI[1024][256]
      long n = j >> 8, k = j & 255;
      int g = (int)((n & 63) >> 4);
      int c = (int)((n >> 6) * 16 + (n & 15));
      WhhI[j] = f2bf(whh[(long)(g * 256 + c) * 256 + k]); continue;
    }
    j -= NHH;
    if (j < NQ) {  // Wqkv[768][256]
      long n = j >> 8, k = j & 255;
      float v = (n < 256) ? wq[n * 256 + k] : (n < 512) ? wk[(n - 256) * 256 + k]
                                                        : wv[(n - 512) * 256 + k];
      Wqkv[j] = f2bf(v); continue;
    }
    j -= NQ;
    if (j < N0P) {  // W0p[512][192] zero-padded
      long n = j / 192, k = j - n * 192;
      W0p[j] = f2bf(k < 160 ? w0[n * 160 + k] : 0.0f); continue;
    }
    j -= N0P;
    if (j < N1) { W1b[j] = f2bf(w1[j]); continue; }
    j -= N1;
    if (j < N2) { W2b[j] = f2bf(w2[j]); continue; }
    j -= N2;
    if (j < N3) { W3b[j] = f2bf(w3[j]); continue; }
    j -= N3;
    if (j < NO) { WoutB[j] = f2bf(wout[j]); continue; }
    j -= NO;
    if (j < NBG) {  // bgI interleaved like WihI rows
      int g = (int)((j & 63) >> 4);
      int c = (int)((j >> 6) * 16 + (j & 15));
      long orig = g * 256 + c;
      bgI[j] = bih[orig] + bhh[orig]; continue;
    }
    j -= NBG;
    bqkv[j] = (j < 256) ? bq[j] : (j < 512) ? bk[j - 256] : bv[j - 512];
  }
}

// ---------------- prep: per-chunk padded concat input (t in [t0, t0+64)) ----------------
__global__ void seqenc_prep_x(
    const float* __restrict__ state, const float* __restrict__ actions,
    u16* __restrict__ XpadC, int t0)
{
  const int TOT = 32768 * 192;
  for (int i = blockIdx.x * blockDim.x + threadIdx.x; i < TOT;
       i += gridDim.x * blockDim.x) {
    int row = i / 192, col = i - row * 192;
    int tl = row >> 9, r = row & 511;
    int t = t0 + tl;
    int b = r >> 3, a = r & 7;
    float v = 0.0f;
    if (col < 128) v = state[((size_t)(b * 256 + t)) * 128 + col];
    else if (col < 160) v = actions[(((size_t)(b * 256 + t)) * 8 + a) * 32 + (col - 128)];
    XpadC[i] = f2bf(v);
  }
}

// ---------------- state init ----------------
__global__ void seqenc_init(const float* __restrict__ h0, const float* __restrict__ c0,
                            u16* __restrict__ hbuf, float* __restrict__ cbuf,
                            float* __restrict__ osum)
{
  int i = blockIdx.x * blockDim.x + threadIdx.x;
  if (i < 512 * 256) {
    hbuf[i] = f2bf(h0[i]);
    cbuf[i] = c0[i];
    osum[i] = 0.0f;
  }
}

// ---------------- unified GEMM (depth-2 pipelined): C = A @ B^T + bias ----------------
// mode 0: bf16 out; 1: bf16 + relu; 2: f32 out; 3: bf16 out, cols>=512 transposed to vT.
__global__ __launch_bounds__(256) void seqenc_gemm(
    const u16* __restrict__ A1, const u16* __restrict__ A2, int K1, int lda,
    const u16* __restrict__ B, const float* __restrict__ bias,
    void* __restrict__ C, int ldc, u16* __restrict__ vT,
    int K, int N, int mode)
{
  __shared__ char As[2][16384];
  __shared__ char Bs[2][16384];
  const int tid = threadIdx.x;
  const int m0 = blockIdx.x * 128, n0 = blockIdx.y * 128;
  const int wid = tid >> 6, lane = tid & 63;
  const int wm = (wid >> 1) * 64, wn = (wid & 1) * 64;
  const int lr = lane & 15, kq = lane >> 4;
  f32x4 acc[4][4] = {};

  auto stage = [&](int tk, int buf) {
    int kt = tk << 6;
    const u16* Abase = (kt < K1) ? (A1 + kt) : (A2 + (kt - K1));
#pragma unroll
    for (int i2 = 0; i2 < 4; ++i2) {
      int q = i2 * 256 + tid;
      int r = q >> 3, cb = (q & 7) << 4;
      int scb = cb ^ SW(r);
      gload_lds16(Abase + (size_t)(m0 + r) * lda + (scb >> 1), As[buf] + q * 16);
      gload_lds16(B + (size_t)(n0 + r) * K + kt + (scb >> 1), Bs[buf] + q * 16);
    }
  };

  const int NT = K >> 6;
  stage(0, 0);
  int cur = 0;
  for (int t = 0; t < NT; ++t) {
    if (t + 1 < NT) { stage(t + 1, cur ^ 1); WAITV(8); }
    else { WAITV(0); }
    RAW_BAR();
#pragma unroll
    for (int ks = 0; ks < 2; ++ks) {
      bf16x8 af[4], bfr[4];
      int kb = ks * 64 + (kq << 4);
#pragma unroll
      for (int tt = 0; tt < 4; ++tt) {
        int ra = wm + tt * 16 + lr;
        af[tt] = *(const bf16x8*)(As[cur] + ra * 128 + (kb ^ SW(ra)));
        int rb = wn + tt * 16 + lr;
        bfr[tt] = *(const bf16x8*)(Bs[cur] + rb * 128 + (kb ^ SW(rb)));
      }
#pragma unroll
      for (int mt = 0; mt < 4; ++mt)
#pragma unroll
        for (int nt = 0; nt < 4; ++nt)
          acc[mt][nt] = __builtin_amdgcn_mfma_f32_16x16x32_bf16(af[mt], bfr[nt], acc[mt][nt], 0, 0, 0);
    }
    RAW_BAR();
    cur ^= 1;
  }

#pragma unroll
  for (int mt = 0; mt < 4; ++mt) {
#pragma unroll
    for (int nt = 0; nt < 4; ++nt) {
      int gn = n0 + wn + nt * 16 + lr;
      float bv = bias[gn];
#pragma unroll
      for (int rr = 0; rr < 4; ++rr) {
        int gm = m0 + wm + mt * 16 + (kq << 2) + rr;
        float v = acc[mt][nt][rr] + bv;
        if (mode == 1) v = fmaxf(v, 0.0f);
        if (mode == 2) {
          ((float*)C)[(size_t)gm * ldc + gn] = v;
        } else if (mode == 3 && gn >= 512) {
          vT[(size_t)(gn - 512) * 512 + gm] = f2bf(v);
        } else {
          ((u16*)C)[(size_t)gm * ldc + gn] = f2bf(v);
        }
      }
    }
  }
}

// ---------------- fused gates GEMM (K=256, h-part only) + LSTM pointwise ----------------
// xWt[512][1024] (f32, gate-interleaved cols, bias pre-added) provides the x-projection.
__global__ __launch_bounds__(256) void seqenc_gates_lstm(
    const u16* __restrict__ hbuf, const u16* __restrict__ WhhI,
    const float* __restrict__ xWt,
    float* __restrict__ cbuf, u16* __restrict__ hq)
{
  __shared__ char As[2][16384];
  __shared__ char Bs[2][16384];
  const int tid = threadIdx.x;
  const int m0 = blockIdx.x * 128, n0 = blockIdx.y * 128;
  const int wid = tid >> 6, lane = tid & 63;
  const int wm = (wid >> 1) * 64, wn = (wid & 1) * 64;
  const int lr = lane & 15, kq = lane >> 4;
  const int nb = n0 + wn;
  const int cg = (nb >> 6) * 16 + lr;

  // early x-projection loads; latency hides under the GEMM (pinned before sched_barrier)
  float xw[4][4][4];
#pragma unroll
  for (int mt = 0; mt < 4; ++mt)
#pragma unroll
    for (int rr = 0; rr < 4; ++rr) {
      int gm = m0 + wm + mt * 16 + (kq << 2) + rr;
      const float* xp = xWt + (size_t)gm * 1024 + nb + lr;
      xw[mt][rr][0] = xp[0];
      xw[mt][rr][1] = xp[16];
      xw[mt][rr][2] = xp[32];
      xw[mt][rr][3] = xp[48];
    }

  f32x4 acc[4][4] = {};
  auto stage = [&](int tk, int buf) {
    int kt = tk << 6;
#pragma unroll
    for (int i2 = 0; i2 < 4; ++i2) {
      int q = i2 * 256 + tid;
      int r = q >> 3, cb = (q & 7) << 4;
      int scb = cb ^ SW(r);
      gload_lds16(hbuf + (size_t)(m0 + r) * 256 + kt + (scb >> 1), As[buf] + q * 16);
      gload_lds16(WhhI + (size_t)(n0 + r) * 256 + kt + (scb >> 1), Bs[buf] + q * 16);
    }
  };

  const int NT = 4;
  stage(0, 0);
  int cur = 0;
  for (int t = 0; t < NT; ++t) {
    if (t + 1 < NT) { stage(t + 1, cur ^ 1); WAITV(8); }
    else { WAITV(0); }
    RAW_BAR();
#pragma unroll
    for (int ks = 0; ks < 2; ++ks) {
      bf16x8 af[4], bfr[4];
      int kb = ks * 64 + (kq << 4);
#pragma unroll
      for (int tt = 0; tt < 4; ++tt) {
        int ra = wm + tt * 16 + lr;
        af[tt] = *(const bf16x8*)(As[cur] + ra * 128 + (kb ^ SW(ra)));
        int rb = wn + tt * 16 + lr;
        bfr[tt] = *(const bf16x8*)(Bs[cur] + rb * 128 + (kb ^ SW(rb)));
      }
#pragma unroll
      for (int mt = 0; mt < 4; ++mt)
#pragma unroll
        for (int nt = 0; nt < 4; ++nt)
          acc[mt][nt] = __builtin_amdgcn_mfma_f32_16x16x32_bf16(af[mt], bfr[nt], acc[mt][nt], 0, 0, 0);
    }
    RAW_BAR();
    cur ^= 1;
  }

  // LSTM epilogue: gates = h-part (acc) + x-part (xw, bias included)
#pragma unroll
  for (int mt = 0; mt < 4; ++mt) {
#pragma unroll
    for (int rr = 0; rr < 4; ++rr) {
      int gm = m0 + wm + mt * 16 + (kq << 2) + rr;
      size_t gi = (size_t)gm * 256 + cg;
      float i_ = fsigmoid(acc[mt][0][rr] + xw[mt][rr][0]);
      float f_ = fsigmoid(acc[mt][1][rr] + xw[mt][rr][1]);
      float g_ = ftanh(acc[mt][2][rr] + xw[mt][rr][2]);
      float o_ = fsigmoid(acc[mt][3][rr] + xw[mt][rr][3]);
      float cn = f_ * cbuf[gi] + i_ * g_;
      float hn = o_ * ftanh(cn);
      cbuf[gi] = cn;
      hq[gi] = f2bf(hn);
    }
  }
}

// ---------------- attention: 32 WGs x 16 rows; pipelined k/v loads ----------------
__global__ __launch_bounds__(512) void seqenc_attn(
    const u16* __restrict__ QKV, const u16* __restrict__ vT,
    const u16* __restrict__ hq, u16* __restrict__ hbuf, float* __restrict__ osum)
{
  __shared__ float scratch[16 * 516];
  __shared__ char spb[16 * 1024];
  const int tid = threadIdx.x;
  const int lane = tid & 63, wid = tid >> 6;
  const int lr = lane & 15, kq = lane >> 4;
  const int r0 = blockIdx.x * 16;

  // preload h' add-operands early (latency hides under S + softmax)
  u16 hql[2][4];
#pragma unroll
  for (int nt = 0; nt < 2; ++nt) {
    const int d0 = wid * 32 + nt * 16;
#pragma unroll
    for (int rr = 0; rr < 4; ++rr)
      hql[nt][rr] = hq[(size_t)(r0 + kq * 4 + rr) * 256 + d0 + lr];
  }

  bf16x8 vfp[8];  // pre-issued PV tile nt=0, ks 0..7

  // S = q @ k^T with explicit 2-deep kf pipeline
  {
    bf16x8 qf[8];
#pragma unroll
    for (int ks = 0; ks < 8; ++ks)
      qf[ks] = *(const bf16x8*)(QKV + (size_t)(r0 + lr) * 768 + ks * 32 + (kq << 3));
    bf16x8 kf[2][8];
    {
      const u16* bp = QKV + (size_t)(wid * 64 + lr) * 768 + 256 + (kq << 3);
#pragma unroll
      for (int ks = 0; ks < 8; ++ks) kf[0][ks] = *(const bf16x8*)(bp + ks * 32);
    }
#pragma unroll
    for (int nt = 0; nt < 4; ++nt) {
      if (nt + 1 < 4) {
        const u16* bpn = QKV + (size_t)(wid * 64 + (nt + 1) * 16 + lr) * 768 + 256 + (kq << 3);
#pragma unroll
        for (int ks = 0; ks < 8; ++ks) kf[(nt + 1) & 1][ks] = *(const bf16x8*)(bpn + ks * 32);
      } else {
        const u16* vp0 = vT + (size_t)(wid * 32 + lr) * 512 + (kq << 3);
#pragma unroll
        for (int ks = 0; ks < 8; ++ks) vfp[ks] = *(const bf16x8*)(vp0 + ks * 32);
      }
      f32x4 a4 = {0.0f, 0.0f, 0.0f, 0.0f};
#pragma unroll
      for (int ks = 0; ks < 8; ++ks)
        a4 = __builtin_amdgcn_mfma_f32_16x16x32_bf16(qf[ks], kf[nt & 1][ks], a4, 0, 0, 0);
      const int key0 = wid * 64 + nt * 16;
#pragma unroll
      for (int rr = 0; rr < 4; ++rr)
        scratch[(kq * 4 + rr) * 516 + key0 + lr] = a4[rr];
    }
  }
  __syncthreads();

  // softmax (row-parallel over 32 lanes)
  {
    int r = tid >> 5, l32 = tid & 31;
    float vals[16];
    float m = -3.4e38f;
#pragma unroll
    for (int j2 = 0; j2 < 16; ++j2) {
      vals[j2] = scratch[r * 516 + l32 + j2 * 32];
      m = fmaxf(m, vals[j2]);
    }
#pragma unroll
    for (int s2 = 16; s2 > 0; s2 >>= 1) m = fmaxf(m, __shfl_xor(m, s2, 32));
    float sum = 0.0f;
#pragma unroll
    for (int j2 = 0; j2 < 16; ++j2) {
      vals[j2] = __expf((vals[j2] - m) * 0.0625f);
      sum += vals[j2];
    }
#pragma unroll
    for (int s2 = 16; s2 > 0; s2 >>= 1) sum += __shfl_xor(sum, s2, 32);
    float inv = 1.0f / sum;
#pragma unroll
    for (int j2 = 0; j2 < 16; ++j2) {
      int c = l32 + j2 * 32;
      *(u16*)(spb + r * 1024 + ((c * 2) ^ SW(r))) = f2bf(vals[j2] * inv);
    }
  }
  __syncthreads();

  // h'' = h' + P @ V (via vT), pipelined vf; osum += h''
  {
    bf16x8 pf[16];
#pragma unroll
    for (int ks = 0; ks < 16; ++ks)
      pf[ks] = *(const bf16x8*)(spb + lr * 1024 + ((ks * 64 + (kq << 4)) ^ SW(lr)));
    const u16* vp = vT + (size_t)(wid * 32 + lr) * 512 + (kq << 3);
    bf16x8 vfb[8];
#pragma unroll
    for (int ks = 0; ks < 8; ++ks) vfb[ks] = *(const bf16x8*)(vp + 256 + ks * 32);
    f32x4 a0 = {0.0f, 0.0f, 0.0f, 0.0f};
#pragma unroll
    for (int ks = 0; ks < 8; ++ks)
      a0 = __builtin_amdgcn_mfma_f32_16x16x32_bf16(pf[ks], vfp[ks], a0, 0, 0, 0);
#pragma unroll
    for (int ks = 0; ks < 8; ++ks) vfp[ks] = *(const bf16x8*)(vp + 8192 + ks * 32);
#pragma unroll
    for (int ks = 0; ks < 8; ++ks)
      a0 = __builtin_amdgcn_mfma_f32_16x16x32_bf16(pf[8 + ks], vfb[ks], a0, 0, 0, 0);
#pragma unroll
    for (int ks = 0; ks < 8; ++ks) vfb[ks] = *(const bf16x8*)(vp + 8448 + ks * 32);
    f32x4 a1 = {0.0f, 0.0f, 0.0f, 0.0f};
#pragma unroll
    for (int ks = 0; ks < 8; ++ks)
      a1 = __builtin_amdgcn_mfma_f32_16x16x32_bf16(pf[ks], vfp[ks], a1, 0, 0, 0);
#pragma unroll
    for (int ks = 0; ks < 8; ++ks)
      a1 = __builtin_amdgcn_mfma_f32_16x16x32_bf16(pf[8 + ks], vfb[ks], a1, 0, 0, 0);
#pragma unroll
    for (int rr = 0; rr < 4; ++rr) {
      int row = kq * 4 + rr;
      int col0 = wid * 32 + lr;
      size_t gi0 = (size_t)(r0 + row) * 256 + col0;
      float hn0 = bf2f(hql[0][rr]) + a0[rr];
      hbuf[gi0] = f2bf(hn0);
      osum[gi0] += hn0;
      size_t gi1 = gi0 + 16;
      float hn1 = bf2f(hql[1][rr]) + a1[rr];
      hbuf[gi1] = f2bf(hn1);
      osum[gi1] += hn1;
    }
  }
}

// ---------------- osum/256 -> bf16 ----------------
__global__ void seqenc_conv(const float* __restrict__ osum, u16* __restrict__ ob)
{
  int i = blockIdx.x * blockDim.x + threadIdx.x;
  if (i < 512 * 256) ob[i] = f2bf(osum[i] * (1.0f / 256.0f));
}

extern "C" void kernel_launch(void* const* d_in, const int* in_sizes, int n_in,
                              void* d_out, int out_size, void* d_ws, size_t ws_size,
                              hipStream_t stream) {
  (void)in_sizes; (void)n_in; (void)out_size; (void)ws_size;
  const float* state = (const float*)d_in[0];
  const float* actions = (const float*)d_in[1];
  const float* h0 = (const float*)d_in[2];
  const float* c0 = (const float*)d_in[3];
  const float* w0 = (const float*)d_in[4];
  const float* b0 = (const float*)d_in[5];
  const float* w1 = (const float*)d_in[6];
  const float* b1 = (const float*)d_in[7];
  const float* w2 = (const float*)d_in[8];
  const float* b2 = (const float*)d_in[9];
  const float* w3 = (const float*)d_in[10];
  const float* b3 = (const float*)d_in[11];
  const float* wih = (const float*)d_in[12];
  const float* whh = (const float*)d_in[13];
  const float* bih = (const float*)d_in[14];
  const float* bhh = (const float*)d_in[15];
  const float* wq = (const float*)d_in[16];
  const float* bq = (const float*)d_in[17];
  const float* wk = (const float*)d_in[18];
  const float* bk = (const float*)d_in[19];
  const float* wv = (const float*)d_in[20];
  const float* bv = (const float*)d_in[21];
  const float* wout = (const float*)d_in[22];
  const float* bout = (const float*)d_in[23];

  char* ws = (char*)d_ws;
  size_t off = 0;
  auto take = [&](size_t bytes) {
    off = (off + 255) & ~(size_t)255;
    char* p = ws + off;
    off += bytes;
    return p;
  };
  u16* XpadC = (u16*)take(32768UL * 192 * 2);
  u16* ping  = (u16*)take(32768UL * 512 * 2);   // MLP intermediate; dead after MLP
  u16* pong  = (u16*)take(32768UL * 512 * 2);   // MLP intermediate; dead after MLP
  float* xW  = (float*)ping;                    // ALIAS: 32-step f32 window [16384][1024] = 67.1 MB
  u16* X4    = (u16*)take(131072UL * 256 * 2);
  u16* W0p   = (u16*)take(512UL * 192 * 2);
  u16* W1b   = (u16*)take(512UL * 512 * 2);
  u16* W2b   = (u16*)take(512UL * 512 * 2);
  u16* W3b   = (u16*)take(256UL * 512 * 2);
  u16* WihI  = (u16*)take(1024UL * 256 * 2);
  u16* WhhI  = (u16*)take(1024UL * 256 * 2);
  u16* Wqkv  = (u16*)take(768UL * 256 * 2);
  u16* WoutB = (u16*)take(256UL * 256 * 2);
  float* bgI   = (float*)take(1024UL * 4);
  float* bqkvp = (float*)take(768UL * 4);
  u16* QKV   = (u16*)take(512UL * 768 * 2);
  u16* vT    = (u16*)take(256UL * 512 * 2);
  u16* hbuf  = (u16*)take(512UL * 256 * 2);   // h'' (post-attn), input to gates
  u16* hq    = (u16*)take(512UL * 256 * 2);   // h' (post-lstm), input to qkv/attn
  float* cbuf  = (float*)take(512UL * 256 * 4);
  float* osum  = (float*)take(512UL * 256 * 4);
  u16* ob    = (u16*)take(512UL * 256 * 2);

  seqenc_prep_w<<<1024, 256, 0, stream>>>(w0, w1, w2, w3, wih, whh, bih, bhh,
                                          wq, wk, wv, bq, bk, bv, wout,
                                          WihI, WhhI, Wqkv, W0p, W1b, W2b, W3b, WoutB, bgI, bqkvp);
  seqenc_init<<<512, 256, 0, stream>>>(h0, c0, hbuf, cbuf, osum);

  const int CM = 32768;
  for (int c = 0; c < 4; ++c) {
    u16* x4c = X4 + (size_t)c * CM * 256;
    seqenc_prep_x<<<2048, 256, 0, stream>>>(state, actions, XpadC, c * 64);
    seqenc_gemm<<<dim3(CM / 128, 4), 256, 0, stream>>>(XpadC, XpadC, 192, 192, W0p, b0, ping, 512, nullptr, 192, 512, 1);
    seqenc_gemm<<<dim3(CM / 128, 4), 256, 0, stream>>>(ping, ping, 512, 512, W1b, b1, pong, 512, nullptr, 512, 512, 1);
    seqenc_gemm<<<dim3(CM / 128, 4), 256, 0, stream>>>(pong, pong, 512, 512, W2b, b2, ping, 512, nullptr, 512, 512, 1);
    seqenc_gemm<<<dim3(CM / 128, 2), 256, 0, stream>>>(ping, ping, 512, 512, W3b, b3, x4c, 256, nullptr, 512, 256, 0);
  }

  // recurrent loop in 8 windows of 32 steps; bulk x-projection per window
  for (int c = 0; c < 8; ++c) {
    const u16* x4w = X4 + (size_t)c * 32 * 512 * 256;
    // xW[16384][1024] = x_window @ WihI^T + bgI  (f32, gate-interleaved cols)
    seqenc_gemm<<<dim3(128, 8), 256, 0, stream>>>(x4w, x4w, 256, 256, WihI, bgI, xW, 1024, nullptr, 256, 1024, 2);
    for (int tt = 0; tt < 32; ++tt) {
      const float* xWt = xW + (size_t)tt * 512 * 1024;
      seqenc_gates_lstm<<<dim3(4, 8), 256, 0, stream>>>(hbuf, WhhI, xWt, cbuf, hq);
      seqenc_gemm<<<dim3(4, 6), 256, 0, stream>>>(hq, hq, 256, 256, Wqkv, bqkvp, QKV, 768, vT, 256, 768, 3);
      seqenc_attn<<<32, 512, 0, stream>>>(QKV, vT, hq, hbuf, osum);
    }
  }

  seqenc_conv<<<512, 256, 0, stream>>>(osum, ob);
  seqenc_gemm<<<dim3(4, 2), 256, 0, stream>>>(ob, ob, 256, 256, WoutB, bout, d_out, 256, nullptr, 256, 256, 2);
}

// Round 16
// 10511.208 us; speedup vs baseline: 1.1537x; 1.0528x over previous
//
#include <hip/hip_runtime.h>

typedef unsigned short u16;
typedef unsigned int u32;
typedef __attribute__((ext_vector_type(8))) short bf16x8;
typedef __attribute__((ext_vector_type(4))) float f32x4;

#define SW(r) (((r) & 7) << 4)
#define RAW_BAR() { __builtin_amdgcn_s_barrier(); __builtin_amdgcn_sched_barrier(0); }
#define WAITV(N) { asm volatile("s_waitcnt vmcnt(" #N ")" ::: "memory"); __builtin_amdgcn_sched_barrier(0); }

__device__ __forceinline__ u16 f2bf(float f) {
  u32 x = __float_as_uint(f);
  x += 0x7fffu + ((x >> 16) & 1u);
  return (u16)(x >> 16);
}
__device__ __forceinline__ float bf2f(u16 h) { return __uint_as_float(((u32)h) << 16); }

__device__ __forceinline__ void gload_lds16(const void* g, void* l) {
  __builtin_amdgcn_global_load_lds(
      (const __attribute__((address_space(1))) u32*)g,
      (__attribute__((address_space(3))) u32*)l, 16, 0, 0);
}

__device__ __forceinline__ float fsigmoid(float x) { return 1.0f / (1.0f + __expf(-x)); }
__device__ __forceinline__ float ftanh(float x) {
  float a = fabsf(x);
  float t = __expf(-2.0f * a);
  float r = (1.0f - t) / (1.0f + t);
  return x < 0.0f ? -r : r;
}

// ---------------- prep: bf16 weight packs ----------------
// WihI/WhhI: gate-interleaved rows n = (c>>4)*64 + g*16 + (c&15), K=256 each.
__global__ void seqenc_prep_w(
    const float* __restrict__ w0, const float* __restrict__ w1,
    const float* __restrict__ w2, const float* __restrict__ w3,
    const float* __restrict__ wih, const float* __restrict__ whh,
    const float* __restrict__ bih, const float* __restrict__ bhh,
    const float* __restrict__ wq, const float* __restrict__ wk, const float* __restrict__ wv,
    const float* __restrict__ bq, const float* __restrict__ bk, const float* __restrict__ bv,
    const float* __restrict__ wout,
    u16* __restrict__ WihI, u16* __restrict__ WhhI, u16* __restrict__ Wqkv,
    u16* __restrict__ W0p, u16* __restrict__ W1b, u16* __restrict__ W2b,
    u16* __restrict__ W3b, u16* __restrict__ WoutB,
    float* __restrict__ bgI, float* __restrict__ bqkv)
{
  const long NIH = 262144L, NHH = 262144L, NQ = 196608L, N0P = 98304L;
  const long N1 = 262144L, N2 = 262144L, N3 = 131072L, NO = 65536L;
  const long NBG = 1024L, NBQ = 768L;
  const long TOT = NIH + NHH + NQ + N0P + N1 + N2 + N3 + NO + NBG + NBQ;
  for (long i = (long)blockIdx.x * blockDim.x + threadIdx.x; i < TOT;
       i += (long)gridDim.x * blockDim.x) {
    long j = i;
    if (j < NIH) {  // WihI[1024][256]
      long n = j >> 8, k = j & 255;
      int g = (int)((n & 63) >> 4);
      int c = (int)((n >> 6) * 16 + (n & 15));
      WihI[j] = f2bf(wih[(long)(g * 256 + c) * 256 + k]); continue;
    }
    j -= NIH;
    if (j < NHH) {  // WhhI[1024][256]
      long n = j >> 8, k = j & 255;
      int g = (int)((n & 63) >> 4);
      int c = (int)((n >> 6) * 16 + (n & 15));
      WhhI[j] = f2bf(whh[(long)(g * 256 + c) * 256 + k]); continue;
    }
    j -= NHH;
    if (j < NQ) {  // Wqkv[768][256]
      long n = j >> 8, k = j & 255;
      float v = (n < 256) ? wq[n * 256 + k] : (n < 512) ? wk[(n - 256) * 256 + k]
                                                        : wv[(n - 512) * 256 + k];
      Wqkv[j] = f2bf(v); continue;
    }
    j -= NQ;
    if (j < N0P) {  // W0p[512][192] zero-padded
      long n = j / 192, k = j - n * 192;
      W0p[j] = f2bf(k < 160 ? w0[n * 160 + k] : 0.0f); continue;
    }
    j -= N0P;
    if (j < N1) { W1b[j] = f2bf(w1[j]); continue; }
    j -= N1;
    if (j < N2) { W2b[j] = f2bf(w2[j]); continue; }
    j -= N2;
    if (j < N3) { W3b[j] = f2bf(w3[j]); continue; }
    j -= N3;
    if (j < NO) { WoutB[j] = f2bf(wout[j]); continue; }
    j -= NO;
    if (j < NBG) {  // bgI interleaved like WihI rows
      int g = (int)((j & 63) >> 4);
      int c = (int)((j >> 6) * 16 + (j & 15));
      long orig = g * 256 + c;
      bgI[j] = bih[orig] + bhh[orig]; continue;
    }
    j -= NBG;
    bqkv[j] = (j < 256) ? bq[j] : (j < 512) ? bk[j - 256] : bv[j - 512];
  }
}

// ---------------- prep: per-chunk padded concat input (t in [t0, t0+64)) ----------------
__global__ void seqenc_prep_x(
    const float* __restrict__ state, const float* __restrict__ actions,
    u16* __restrict__ XpadC, int t0)
{
  const int TOT = 32768 * 192;
  for (int i = blockIdx.x * blockDim.x + threadIdx.x; i < TOT;
       i += gridDim.x * blockDim.x) {
    int row = i / 192, col = i - row * 192;
    int tl = row >> 9, r = row & 511;
    int t = t0 + tl;
    int b = r >> 3, a = r & 7;
    float v = 0.0f;
    if (col < 128) v = state[((size_t)(b * 256 + t)) * 128 + col];
    else if (col < 160) v = actions[(((size_t)(b * 256 + t)) * 8 + a) * 32 + (col - 128)];
    XpadC[i] = f2bf(v);
  }
}

// ---------------- state init ----------------
__global__ void seqenc_init(const float* __restrict__ h0, const float* __restrict__ c0,
                            u16* __restrict__ hbuf, float* __restrict__ cbuf,
                            float* __restrict__ osum)
{
  int i = blockIdx.x * blockDim.x + threadIdx.x;
  if (i < 512 * 256) {
    hbuf[i] = f2bf(h0[i]);
    cbuf[i] = c0[i];
    osum[i] = 0.0f;
  }
}

// ---------------- unified GEMM (depth-2 pipelined, BK=64): modes 0/1/2 ----------------
__global__ __launch_bounds__(256) void seqenc_gemm(
    const u16* __restrict__ A1, const u16* __restrict__ A2, int K1, int lda,
    const u16* __restrict__ B, const float* __restrict__ bias,
    void* __restrict__ C, int ldc,
    int K, int N, int mode)
{
  __shared__ char As[2][16384];
  __shared__ char Bs[2][16384];
  const int tid = threadIdx.x;
  const int m0 = blockIdx.x * 128, n0 = blockIdx.y * 128;
  const int wid = tid >> 6, lane = tid & 63;
  const int wm = (wid >> 1) * 64, wn = (wid & 1) * 64;
  const int lr = lane & 15, kq = lane >> 4;
  f32x4 acc[4][4] = {};

  auto stage = [&](int tk, int buf) {
    int kt = tk << 6;
    const u16* Abase = (kt < K1) ? (A1 + kt) : (A2 + (kt - K1));
#pragma unroll
    for (int i2 = 0; i2 < 4; ++i2) {
      int q = i2 * 256 + tid;
      int r = q >> 3, cb = (q & 7) << 4;
      int scb = cb ^ SW(r);
      gload_lds16(Abase + (size_t)(m0 + r) * lda + (scb >> 1), As[buf] + q * 16);
      gload_lds16(B + (size_t)(n0 + r) * K + kt + (scb >> 1), Bs[buf] + q * 16);
    }
  };

  const int NT = K >> 6;
  stage(0, 0);
  int cur = 0;
  for (int t = 0; t < NT; ++t) {
    if (t + 1 < NT) { stage(t + 1, cur ^ 1); WAITV(8); }
    else { WAITV(0); }
    RAW_BAR();
#pragma unroll
    for (int ks = 0; ks < 2; ++ks) {
      bf16x8 af[4], bfr[4];
      int kb = ks * 64 + (kq << 4);
#pragma unroll
      for (int tt = 0; tt < 4; ++tt) {
        int ra = wm + tt * 16 + lr;
        af[tt] = *(const bf16x8*)(As[cur] + ra * 128 + (kb ^ SW(ra)));
        int rb = wn + tt * 16 + lr;
        bfr[tt] = *(const bf16x8*)(Bs[cur] + rb * 128 + (kb ^ SW(rb)));
      }
#pragma unroll
      for (int mt = 0; mt < 4; ++mt)
#pragma unroll
        for (int nt = 0; nt < 4; ++nt)
          acc[mt][nt] = __builtin_amdgcn_mfma_f32_16x16x32_bf16(af[mt], bfr[nt], acc[mt][nt], 0, 0, 0);
    }
    RAW_BAR();
    cur ^= 1;
  }

#pragma unroll
  for (int mt = 0; mt < 4; ++mt) {
#pragma unroll
    for (int nt = 0; nt < 4; ++nt) {
      int gn = n0 + wn + nt * 16 + lr;
      float bv = bias[gn];
#pragma unroll
      for (int rr = 0; rr < 4; ++rr) {
        int gm = m0 + wm + mt * 16 + (kq << 2) + rr;
        float v = acc[mt][nt][rr] + bv;
        if (mode == 1) v = fmaxf(v, 0.0f);
        if (mode == 2) ((float*)C)[(size_t)gm * ldc + gn] = v;
        else ((u16*)C)[(size_t)gm * ldc + gn] = f2bf(v);
      }
    }
  }
}

// ---------------- qkv GEMM (K=256, BK=128, 2 rounds), v transposed to vT ----------------
__global__ __launch_bounds__(256) void seqenc_qkv(
    const u16* __restrict__ A, const u16* __restrict__ B,
    const float* __restrict__ bias, u16* __restrict__ C, u16* __restrict__ vT)
{
  __shared__ char As[2][32768];
  __shared__ char Bs[2][32768];
  const int tid = threadIdx.x;
  const int m0 = blockIdx.x * 128, n0 = blockIdx.y * 128;
  const int wid = tid >> 6, lane = tid & 63;
  const int wm = (wid >> 1) * 64, wn = (wid & 1) * 64;
  const int lr = lane & 15, kq = lane >> 4;
  f32x4 acc[4][4] = {};

  auto stage = [&](int tk, int buf) {
    int kt = tk << 7;
#pragma unroll
    for (int i2 = 0; i2 < 8; ++i2) {
      int q = i2 * 256 + tid;
      int r = q >> 4, cb = (q & 15) << 4;
      int scb = cb ^ SW(r);
      gload_lds16(A + (size_t)(m0 + r) * 256 + kt + (scb >> 1), As[buf] + q * 16);
      gload_lds16(B + (size_t)(n0 + r) * 256 + kt + (scb >> 1), Bs[buf] + q * 16);
    }
  };

  stage(0, 0);
  int cur = 0;
  for (int t = 0; t < 2; ++t) {
    if (t + 1 < 2) { stage(1, 1); WAITV(16); }
    else { WAITV(0); }
    RAW_BAR();
#pragma unroll
    for (int ks = 0; ks < 4; ++ks) {
      bf16x8 af[4], bfr[4];
      int kb = ks * 64 + (kq << 4);
#pragma unroll
      for (int tt = 0; tt < 4; ++tt) {
        int ra = wm + tt * 16 + lr;
        af[tt] = *(const bf16x8*)(As[cur] + ra * 256 + (kb ^ SW(ra)));
        int rb = wn + tt * 16 + lr;
        bfr[tt] = *(const bf16x8*)(Bs[cur] + rb * 256 + (kb ^ SW(rb)));
      }
#pragma unroll
      for (int mt = 0; mt < 4; ++mt)
#pragma unroll
        for (int nt = 0; nt < 4; ++nt)
          acc[mt][nt] = __builtin_amdgcn_mfma_f32_16x16x32_bf16(af[mt], bfr[nt], acc[mt][nt], 0, 0, 0);
    }
    RAW_BAR();
    cur ^= 1;
  }

#pragma unroll
  for (int mt = 0; mt < 4; ++mt) {
#pragma unroll
    for (int nt = 0; nt < 4; ++nt) {
      int gn = n0 + wn + nt * 16 + lr;
      float bv = bias[gn];
#pragma unroll
      for (int rr = 0; rr < 4; ++rr) {
        int gm = m0 + wm + mt * 16 + (kq << 2) + rr;
        float v = acc[mt][nt][rr] + bv;
        if (gn >= 512) vT[(size_t)(gn - 512) * 512 + gm] = f2bf(v);
        else C[(size_t)gm * 768 + gn] = f2bf(v);
      }
    }
  }
}

// ---------------- fused gates GEMM (K=256, BK=128, 2 rounds) + LSTM pointwise ----------------
// xWt[512][1024] (f32, gate-interleaved cols, bias pre-added) provides the x-projection.
__global__ __launch_bounds__(256) void seqenc_gates_lstm(
    const u16* __restrict__ hbuf, const u16* __restrict__ WhhI,
    const float* __restrict__ xWt,
    float* __restrict__ cbuf, u16* __restrict__ hq)
{
  __shared__ char As[2][32768];
  __shared__ char Bs[2][32768];
  const int tid = threadIdx.x;
  const int m0 = blockIdx.x * 128, n0 = blockIdx.y * 128;
  const int wid = tid >> 6, lane = tid & 63;
  const int wm = (wid >> 1) * 64, wn = (wid & 1) * 64;
  const int lr = lane & 15, kq = lane >> 4;
  const int nb = n0 + wn;
  const int cg = (nb >> 6) * 16 + lr;

  // early x-projection loads (16 per thread); pinned before staging so WAITV
  // accounting stays exact: [xw 16][stage0 16][stage1 16] -> WAITV(16) drains xw+stage0
  float xw[4][4][4];
#pragma unroll
  for (int mt = 0; mt < 4; ++mt)
#pragma unroll
    for (int rr = 0; rr < 4; ++rr) {
      int gm = m0 + wm + mt * 16 + (kq << 2) + rr;
      const float* xp = xWt + (size_t)gm * 1024 + nb + lr;
      xw[mt][rr][0] = xp[0];
      xw[mt][rr][1] = xp[16];
      xw[mt][rr][2] = xp[32];
      xw[mt][rr][3] = xp[48];
    }
  __builtin_amdgcn_sched_barrier(0);

  f32x4 acc[4][4] = {};
  auto stage = [&](int tk, int buf) {
    int kt = tk << 7;
#pragma unroll
    for (int i2 = 0; i2 < 8; ++i2) {
      int q = i2 * 256 + tid;
      int r = q >> 4, cb = (q & 15) << 4;
      int scb = cb ^ SW(r);
      gload_lds16(hbuf + (size_t)(m0 + r) * 256 + kt + (scb >> 1), As[buf] + q * 16);
      gload_lds16(WhhI + (size_t)(n0 + r) * 256 + kt + (scb >> 1), Bs[buf] + q * 16);
    }
  };

  stage(0, 0);
  int cur = 0;
  for (int t = 0; t < 2; ++t) {
    if (t + 1 < 2) { stage(1, 1); WAITV(16); }
    else { WAITV(0); }
    RAW_BAR();
#pragma unroll
    for (int ks = 0; ks < 4; ++ks) {
      bf16x8 af[4], bfr[4];
      int kb = ks * 64 + (kq << 4);
#pragma unroll
      for (int tt = 0; tt < 4; ++tt) {
        int ra = wm + tt * 16 + lr;
        af[tt] = *(const bf16x8*)(As[cur] + ra * 256 + (kb ^ SW(ra)));
        int rb = wn + tt * 16 + lr;
        bfr[tt] = *(const bf16x8*)(Bs[cur] + rb * 256 + (kb ^ SW(rb)));
      }
#pragma unroll
      for (int mt = 0; mt < 4; ++mt)
#pragma unroll
        for (int nt = 0; nt < 4; ++nt)
          acc[mt][nt] = __builtin_amdgcn_mfma_f32_16x16x32_bf16(af[mt], bfr[nt], acc[mt][nt], 0, 0, 0);
    }
    RAW_BAR();
    cur ^= 1;
  }

  // LSTM epilogue: gates = h-part (acc) + x-part (xw, bias included)
#pragma unroll
  for (int mt = 0; mt < 4; ++mt) {
#pragma unroll
    for (int rr = 0; rr < 4; ++rr) {
      int gm = m0 + wm + mt * 16 + (kq << 2) + rr;
      size_t gi = (size_t)gm * 256 + cg;
      float i_ = fsigmoid(acc[mt][0][rr] + xw[mt][rr][0]);
      float f_ = fsigmoid(acc[mt][1][rr] + xw[mt][rr][1]);
      float g_ = ftanh(acc[mt][2][rr] + xw[mt][rr][2]);
      float o_ = fsigmoid(acc[mt][3][rr] + xw[mt][rr][3]);
      float cn = f_ * cbuf[gi] + i_ * g_;
      float hn = o_ * ftanh(cn);
      cbuf[gi] = cn;
      hq[gi] = f2bf(hn);
    }
  }
}

// ---------------- attention: 32 WGs x 16 rows; pipelined k/v loads ----------------
__global__ __launch_bounds__(512) void seqenc_attn(
    const u16* __restrict__ QKV, const u16* __restrict__ vT,
    const u16* __restrict__ hq, u16* __restrict__ hbuf, float* __restrict__ osum)
{
  __shared__ float scratch[16 * 516];
  __shared__ char spb[16 * 1024];
  const int tid = threadIdx.x;
  const int lane = tid & 63, wid = tid >> 6;
  const int lr = lane & 15, kq = lane >> 4;
  const int r0 = blockIdx.x * 16;

  // preload h' add-operands early (latency hides under S + softmax)
  u16 hql[2][4];
#pragma unroll
  for (int nt = 0; nt < 2; ++nt) {
    const int d0 = wid * 32 + nt * 16;
#pragma unroll
    for (int rr = 0; rr < 4; ++rr)
      hql[nt][rr] = hq[(size_t)(r0 + kq * 4 + rr) * 256 + d0 + lr];
  }

  bf16x8 vfp[8];  // pre-issued PV tile nt=0, ks 0..7

  // S = q @ k^T with explicit 2-deep kf pipeline
  {
    bf16x8 qf[8];
#pragma unroll
    for (int ks = 0; ks < 8; ++ks)
      qf[ks] = *(const bf16x8*)(QKV + (size_t)(r0 + lr) * 768 + ks * 32 + (kq << 3));
    bf16x8 kf[2][8];
    {
      const u16* bp = QKV + (size_t)(wid * 64 + lr) * 768 + 256 + (kq << 3);
#pragma unroll
      for (int ks = 0; ks < 8; ++ks) kf[0][ks] = *(const bf16x8*)(bp + ks * 32);
    }
#pragma unroll
    for (int nt = 0; nt < 4; ++nt) {
      if (nt + 1 < 4) {
        const u16* bpn = QKV + (size_t)(wid * 64 + (nt + 1) * 16 + lr) * 768 + 256 + (kq << 3);
#pragma unroll
        for (int ks = 0; ks < 8; ++ks) kf[(nt + 1) & 1][ks] = *(const bf16x8*)(bpn + ks * 32);
      } else {
        const u16* vp0 = vT + (size_t)(wid * 32 + lr) * 512 + (kq << 3);
#pragma unroll
        for (int ks = 0; ks < 8; ++ks) vfp[ks] = *(const bf16x8*)(vp0 + ks * 32);
      }
      f32x4 a4 = {0.0f, 0.0f, 0.0f, 0.0f};
#pragma unroll
      for (int ks = 0; ks < 8; ++ks)
        a4 = __builtin_amdgcn_mfma_f32_16x16x32_bf16(qf[ks], kf[nt & 1][ks], a4, 0, 0, 0);
      const int key0 = wid * 64 + nt * 16;
#pragma unroll
      for (int rr = 0; rr < 4; ++rr)
        scratch[(kq * 4 + rr) * 516 + key0 + lr] = a4[rr];
    }
  }
  __syncthreads();

  // softmax (row-parallel over 32 lanes)
  {
    int r = tid >> 5, l32 = tid & 31;
    float vals[16];
    float m = -3.4e38f;
#pragma unroll
    for (int j2 = 0; j2 < 16; ++j2) {
      vals[j2] = scratch[r * 516 + l32 + j2 * 32];
      m = fmaxf(m, vals[j2]);
    }
#pragma unroll
    for (int s2 = 16; s2 > 0; s2 >>= 1) m = fmaxf(m, __shfl_xor(m, s2, 32));
    float sum = 0.0f;
#pragma unroll
    for (int j2 = 0; j2 < 16; ++j2) {
      vals[j2] = __expf((vals[j2] - m) * 0.0625f);
      sum += vals[j2];
    }
#pragma unroll
    for (int s2 = 16; s2 > 0; s2 >>= 1) sum += __shfl_xor(sum, s2, 32);
    float inv = 1.0f / sum;
#pragma unroll
    for (int j2 = 0; j2 < 16; ++j2) {
      int c = l32 + j2 * 32;
      *(u16*)(spb + r * 1024 + ((c * 2) ^ SW(r))) = f2bf(vals[j2] * inv);
    }
  }
  __syncthreads();

  // h'' = h' + P @ V (via vT), pipelined vf; osum += h''
  {
    bf16x8 pf[16];
#pragma unroll
    for (int ks = 0; ks < 16; ++ks)
      pf[ks] = *(const bf16x8*)(spb + lr * 1024 + ((ks * 64 + (kq << 4)) ^ SW(lr)));
    const u16* vp = vT + (size_t)(wid * 32 + lr) * 512 + (kq << 3);
    bf16x8 vfb[8];
#pragma unroll
    for (int ks = 0; ks < 8; ++ks) vfb[ks] = *(const bf16x8*)(vp + 256 + ks * 32);
    f32x4 a0 = {0.0f, 0.0f, 0.0f, 0.0f};
#pragma unroll
    for (int ks = 0; ks < 8; ++ks)
      a0 = __builtin_amdgcn_mfma_f32_16x16x32_bf16(pf[ks], vfp[ks], a0, 0, 0, 0);
#pragma unroll
    for (int ks = 0; ks < 8; ++ks) vfp[ks] = *(const bf16x8*)(vp + 8192 + ks * 32);
#pragma unroll
    for (int ks = 0; ks < 8; ++ks)
      a0 = __builtin_amdgcn_mfma_f32_16x16x32_bf16(pf[8 + ks], vfb[ks], a0, 0, 0, 0);
#pragma unroll
    for (int ks = 0; ks < 8; ++ks) vfb[ks] = *(const bf16x8*)(vp + 8448 + ks * 32);
    f32x4 a1 = {0.0f, 0.0f, 0.0f, 0.0f};
#pragma unroll
    for (int ks = 0; ks < 8; ++ks)
      a1 = __builtin_amdgcn_mfma_f32_16x16x32_bf16(pf[ks], vfp[ks], a1, 0, 0, 0);
#pragma unroll
    for (int ks = 0; ks < 8; ++ks)
      a1 = __builtin_amdgcn_mfma_f32_16x16x32_bf16(pf[8 + ks], vfb[ks], a1, 0, 0, 0);
#pragma unroll
    for (int rr = 0; rr < 4; ++rr) {
      int row = kq * 4 + rr;
      int col0 = wid * 32 + lr;
      size_t gi0 = (size_t)(r0 + row) * 256 + col0;
      float hn0 = bf2f(hql[0][rr]) + a0[rr];
      hbuf[gi0] = f2bf(hn0);
      osum[gi0] += hn0;
      size_t gi1 = gi0 + 16;
      float hn1 = bf2f(hql[1][rr]) + a1[rr];
      hbuf[gi1] = f2bf(hn1);
      osum[gi1] += hn1;
    }
  }
}

// ---------------- osum/256 -> bf16 ----------------
__global__ void seqenc_conv(const float* __restrict__ osum, u16* __restrict__ ob)
{
  int i = blockIdx.x * blockDim.x + threadIdx.x;
  if (i < 512 * 256) ob[i] = f2bf(osum[i] * (1.0f / 256.0f));
}

extern "C" void kernel_launch(void* const* d_in, const int* in_sizes, int n_in,
                              void* d_out, int out_size, void* d_ws, size_t ws_size,
                              hipStream_t stream) {
  (void)in_sizes; (void)n_in; (void)out_size; (void)ws_size;
  const float* state = (const float*)d_in[0];
  const float* actions = (const float*)d_in[1];
  const float* h0 = (const float*)d_in[2];
  const float* c0 = (const float*)d_in[3];
  const float* w0 = (const float*)d_in[4];
  const float* b0 = (const float*)d_in[5];
  const float* w1 = (const float*)d_in[6];
  const float* b1 = (const float*)d_in[7];
  const float* w2 = (const float*)d_in[8];
  const float* b2 = (const float*)d_in[9];
  const float* w3 = (const float*)d_in[10];
  const float* b3 = (const float*)d_in[11];
  const float* wih = (const float*)d_in[12];
  const float* whh = (const float*)d_in[13];
  const float* bih = (const float*)d_in[14];
  const float* bhh = (const float*)d_in[15];
  const float* wq = (const float*)d_in[16];
  const float* bq = (const float*)d_in[17];
  const float* wk = (const float*)d_in[18];
  const float* bk = (const float*)d_in[19];
  const float* wv = (const float*)d_in[20];
  const float* bv = (const float*)d_in[21];
  const float* wout = (const float*)d_in[22];
  const float* bout = (const float*)d_in[23];

  char* ws = (char*)d_ws;
  size_t off = 0;
  auto take = [&](size_t bytes) {
    off = (off + 255) & ~(size_t)255;
    char* p = ws + off;
    off += bytes;
    return p;
  };
  u16* XpadC = (u16*)take(32768UL * 192 * 2);
  u16* ping  = (u16*)take(32768UL * 512 * 2);   // MLP intermediate; dead after MLP
  u16* pong  = (u16*)take(32768UL * 512 * 2);   // MLP intermediate; dead after MLP
  float* xW  = (float*)ping;                    // ALIAS: 32-step f32 window [16384][1024]
  u16* X4    = (u16*)take(131072UL * 256 * 2);
  u16* W0p   = (u16*)take(512UL * 192 * 2);
  u16* W1b   = (u16*)take(512UL * 512 * 2);
  u16* W2b   = (u16*)take(512UL * 512 * 2);
  u16* W3b   = (u16*)take(256UL * 512 * 2);
  u16* WihI  = (u16*)take(1024UL * 256 * 2);
  u16* WhhI  = (u16*)take(1024UL * 256 * 2);
  u16* Wqkv  = (u16*)take(768UL * 256 * 2);
  u16* WoutB = (u16*)take(256UL * 256 * 2);
  float* bgI   = (float*)take(1024UL * 4);
  float* bqkvp = (float*)take(768UL * 4);
  u16* QKV   = (u16*)take(512UL * 768 * 2);
  u16* vT    = (u16*)take(256UL * 512 * 2);
  u16* hbuf  = (u16*)take(512UL * 256 * 2);   // h'' (post-attn), input to gates
  u16* hq    = (u16*)take(512UL * 256 * 2);   // h' (post-lstm), input to qkv/attn
  float* cbuf  = (float*)take(512UL * 256 * 4);
  float* osum  = (float*)take(512UL * 256 * 4);
  u16* ob    = (u16*)take(512UL * 256 * 2);

  seqenc_prep_w<<<1024, 256, 0, stream>>>(w0, w1, w2, w3, wih, whh, bih, bhh,
                                          wq, wk, wv, bq, bk, bv, wout,
                                          WihI, WhhI, Wqkv, W0p, W1b, W2b, W3b, WoutB, bgI, bqkvp);
  seqenc_init<<<512, 256, 0, stream>>>(h0, c0, hbuf, cbuf, osum);

  const int CM = 32768;
  for (int c = 0; c < 4; ++c) {
    u16* x4c = X4 + (size_t)c * CM * 256;
    seqenc_prep_x<<<2048, 256, 0, stream>>>(state, actions, XpadC, c * 64);
    seqenc_gemm<<<dim3(CM / 128, 4), 256, 0, stream>>>(XpadC, XpadC, 192, 192, W0p, b0, ping, 512, 192, 512, 1);
    seqenc_gemm<<<dim3(CM / 128, 4), 256, 0, stream>>>(ping, ping, 512, 512, W1b, b1, pong, 512, 512, 512, 1);
    seqenc_gemm<<<dim3(CM / 128, 4), 256, 0, stream>>>(pong, pong, 512, 512, W2b, b2, ping, 512, 512, 512, 1);
    seqenc_gemm<<<dim3(CM / 128, 2), 256, 0, stream>>>(ping, ping, 512, 512, W3b, b3, x4c, 256, 512, 256, 0);
  }

  // recurrent loop in 8 windows of 32 steps; bulk x-projection per window
  for (int c = 0; c < 8; ++c) {
    const u16* x4w = X4 + (size_t)c * 32 * 512 * 256;
    seqenc_gemm<<<dim3(128, 8), 256, 0, stream>>>(x4w, x4w, 256, 256, WihI, bgI, xW, 1024, 256, 1024, 2);
    for (int tt = 0; tt < 32; ++tt) {
      const float* xWt = xW + (size_t)tt * 512 * 1024;
      seqenc_gates_lstm<<<dim3(4, 8), 256, 0, stream>>>(hbuf, WhhI, xWt, cbuf, hq);
      seqenc_qkv<<<dim3(4, 6), 256, 0, stream>>>(hq, Wqkv, bqkvp, QKV, vT);
      seqenc_attn<<<32, 512, 0, stream>>>(QKV, vT, hq, hbuf, osum);
    }
  }

  seqenc_conv<<<512, 256, 0, stream>>>(osum, ob);
  seqenc_gemm<<<dim3(4, 2), 256, 0, stream>>>(ob, ob, 256, 256, WoutB, bout, d_out, 256, 256, 256, 2);
}